// Round 5
// baseline (11501.746 us; speedup 1.0000x reference)
//
#include <hip/hip_runtime.h>
#include <cmath>

#define NH 2048
#define NI 96

// ---------------- GEMM: xin[b,t,:] = x[b,t,:] @ x2h  (no bias; bias added in seq kernel
// to match reference association order (xmul + smul) + bias) ----------------
__global__ __launch_bounds__(256) void xin_gemm(
    const float* __restrict__ A,
    const float* __restrict__ Bm,
    float* __restrict__ C)
{
    __shared__ float At[96][68];  // transposed A tile: At[k][r]
    __shared__ float Bt[96][68];  // Bt[k][c]
    const int tid = threadIdx.x;
    const int rowBase = blockIdx.y * 64;
    const int colBase = blockIdx.x * 64;

    {
        const int r = tid >> 2;
        const int sub = tid & 3;
        const float4* Arow = reinterpret_cast<const float4*>(A + (size_t)(rowBase + r) * NI);
        #pragma unroll
        for (int q = 0; q < 6; ++q) {
            const int k4 = sub + 4 * q;      // 0..23
            float4 v = Arow[k4];
            At[k4 * 4 + 0][r] = v.x;
            At[k4 * 4 + 1][r] = v.y;
            At[k4 * 4 + 2][r] = v.z;
            At[k4 * 4 + 3][r] = v.w;
        }
    }
    {
        const int c4 = tid & 15;
        const int k0 = tid >> 4;
        #pragma unroll
        for (int g = 0; g < 6; ++g) {
            const int kk = k0 + 16 * g;      // 0..95
            float4 v = *reinterpret_cast<const float4*>(Bm + (size_t)kk * NH + colBase + c4 * 4);
            *reinterpret_cast<float4*>(&Bt[kk][c4 * 4]) = v;
        }
    }
    __syncthreads();

    const int ty = tid >> 4, tx = tid & 15;
    float acc[4][4] = {};
    #pragma unroll 8
    for (int kk = 0; kk < 96; ++kk) {
        float4 a = *reinterpret_cast<const float4*>(&At[kk][ty * 4]);
        float4 b = *reinterpret_cast<const float4*>(&Bt[kk][tx * 4]);
        acc[0][0] += a.x * b.x; acc[0][1] += a.x * b.y; acc[0][2] += a.x * b.z; acc[0][3] += a.x * b.w;
        acc[1][0] += a.y * b.x; acc[1][1] += a.y * b.y; acc[1][2] += a.y * b.z; acc[1][3] += a.y * b.w;
        acc[2][0] += a.z * b.x; acc[2][1] += a.z * b.y; acc[2][2] += a.z * b.z; acc[2][3] += a.z * b.w;
        acc[3][0] += a.w * b.x; acc[3][1] += a.w * b.y; acc[3][2] += a.w * b.z; acc[3][3] += a.w * b.w;
    }
    #pragma unroll
    for (int i = 0; i < 4; ++i) {
        float4 o;
        o.x = acc[i][0]; o.y = acc[i][1]; o.z = acc[i][2]; o.w = acc[i][3];
        *reinterpret_cast<float4*>(C + (size_t)(rowBase + ty * 4 + i) * NH + colBase + tx * 4) = o;
    }
}

// ---------------- Sequential recurrence ----------------
// NB batches per block (NB=2: 1024 threads, threads 0-511 = batch 2i,
// 512-1023 = batch 2i+1; each half has its OWN list/wcnt/xstage, so the
// per-batch code path and arithmetic order are IDENTICAL to the NB=1 kernel
// -> bit-exact). Co-locating two independent recurrences on one CU gives
// 4 waves/SIMD from 2 independent dependency chains: one half's LLC-latency
// gather stall is overlapped by the other half's loads + VALU work, and the
// two barriers per step are amortized over 2 batches. LDS 148 KB forces
// 1 block/CU (the co-location we want).
// Per half: 512 threads; thread owns 4 neurons n0=4*tl .. n0+3. xin staged
// through LDS in 4-step chunks (double-buffered); gather row indices
// readfirstlane'd to SGPR base (saddr loads); 4-stage rotated load pipeline.
// Accumulation order: row at list position k -> a[k%4] for k<n4, tail rows
// fold into a0 in list order; reduce tree unchanged.
template <int USE_XIN, int NB>
__global__ __launch_bounds__(NB * 512) void esn_seq(
    const float* __restrict__ xin,   // [B*T*NH] (xmul only) if USE_XIN
    const float* __restrict__ x,     // [B*T*NI] for fallback
    const float* __restrict__ x2h,   // [NI*NH]
    const float* __restrict__ h2h,   // [NH*NH]
    const float* __restrict__ bias,  // [NH]
    float* __restrict__ out,         // [B*NH]
    int T)
{
    const int tid = threadIdx.x;
    const int hb = (NB == 2) ? (tid >> 9) : 0;     // which half/batch
    const int tl = (NB == 2) ? (tid & 511) : tid;  // thread-in-half
    const int b = blockIdx.x * NB + hb;
    const int n0 = tl * 4;
    const int wv = tl >> 6;          // wave within half (0..7)
    const int lane = tid & 63;

    __shared__ alignas(16) int list[NB][NH];
    __shared__ alignas(16) int wcnt[NB][8];
    __shared__ float xt[NB][NI];
    __shared__ alignas(16) float xstage[NB][2][4][NH];  // per half: 2 bufs x 4 steps

    constexpr float DT = 0.075f;
    constexpr float TAU_M = 0.5f;
    constexpr float GGAMMA = 2.7f;
    constexpr float GEPS = 4.7f;
    constexpr float GAIN = 5.0f;
    const float ref_decay = expf(-0.075f / 0.25f);

    float lv[4] = {0.f, 0.f, 0.f, 0.f};
    float hy[4] = {0.f, 0.f, 0.f, 0.f};
    float hz[4] = {0.f, 0.f, 0.f, 0.f};
    float rf[4] = {0.f, 0.f, 0.f, 0.f};
    float cnt[4] = {0.f, 0.f, 0.f, 0.f};
    float bs[4];
    {
        const float4 b4 = *reinterpret_cast<const float4*>(&bias[n0]);
        bs[0] = b4.x; bs[1] = b4.y; bs[2] = b4.z; bs[3] = b4.w;
    }
    int nact = 0;

    const float* __restrict__ xrow = USE_XIN ? (xin + (size_t)b * T * NH + n0) : xin;

    // chunk-staging registers: hold the NEXT chunk (4 rows) of this thread's
    // 4 xin columns; written to LDS at the next boundary.
    float4 P0, P1, P2, P3;

    if (USE_XIN) {
        #pragma unroll
        for (int r = 0; r < 4; ++r) {
            float4 v = *reinterpret_cast<const float4*>(xrow + (size_t)r * NH);
            *reinterpret_cast<float4*>(&xstage[hb][0][r][n0]) = v;
        }
        P0 = *reinterpret_cast<const float4*>(xrow + (size_t)4 * NH);
        P1 = *reinterpret_cast<const float4*>(xrow + (size_t)5 * NH);
        P2 = *reinterpret_cast<const float4*>(xrow + (size_t)6 * NH);
        P3 = *reinterpret_cast<const float4*>(xrow + (size_t)7 * NH);
    } else {
        if (tl < NI) xt[hb][tl] = x[(size_t)b * T * NI + tl];
    }
    __syncthreads();

    const unsigned long long below = (1ull << lane) - 1ull;
    const unsigned long long lo32 = 0xFFFFFFFFull;
    const unsigned long long mb = (lane >= 32) ? (below & ~lo32) : below;

    const int4* __restrict__ L4 = reinterpret_cast<const int4*>(&list[hb][0]);

// pipeline stage macros: ISSUE reads 1 int4 of indices (half-uniform ->
// readfirstlane to SGPR base) + 4 h2h rows (float4 each); ACC folds the stage
// into accumulators with the fixed pos%4 -> a{0..3} mapping.
#define ISSUE(St, grp) do {                                                              \
        I##St = L4[(grp)];                                                               \
        const float* pr0 = h2h + (size_t)__builtin_amdgcn_readfirstlane(I##St.x) * NH;   \
        const float* pr1 = h2h + (size_t)__builtin_amdgcn_readfirstlane(I##St.y) * NH;   \
        const float* pr2 = h2h + (size_t)__builtin_amdgcn_readfirstlane(I##St.z) * NH;   \
        const float* pr3 = h2h + (size_t)__builtin_amdgcn_readfirstlane(I##St.w) * NH;   \
        W##St##_0 = *reinterpret_cast<const float4*>(pr0 + n0);                          \
        W##St##_1 = *reinterpret_cast<const float4*>(pr1 + n0);                          \
        W##St##_2 = *reinterpret_cast<const float4*>(pr2 + n0);                          \
        W##St##_3 = *reinterpret_cast<const float4*>(pr3 + n0);                          \
    } while (0)
#define ACC(St) do {                                                                  \
        a0[0] += W##St##_0.x; a0[1] += W##St##_0.y; a0[2] += W##St##_0.z; a0[3] += W##St##_0.w; \
        a1[0] += W##St##_1.x; a1[1] += W##St##_1.y; a1[2] += W##St##_1.z; a1[3] += W##St##_1.w; \
        a2[0] += W##St##_2.x; a2[1] += W##St##_2.y; a2[2] += W##St##_2.z; a2[3] += W##St##_2.w; \
        a3[0] += W##St##_3.x; a3[1] += W##St##_3.y; a3[2] += W##St##_3.z; a3[3] += W##St##_3.w; \
    } while (0)

    for (int t = 0; t < T; ++t) {
        // ---- current step's xin row: LDS read, hidden under the gather.
        float4 xi;
        if (USE_XIN) xi = *reinterpret_cast<const float4*>(&xstage[hb][(t >> 2) & 1][t & 3][n0]);

        // ---- phase 1: pipelined gather over active rows (prev step's s)
        float a0[4] = {0.f, 0.f, 0.f, 0.f};
        float a1[4] = {0.f, 0.f, 0.f, 0.f};
        float a2[4] = {0.f, 0.f, 0.f, 0.f};
        float a3[4] = {0.f, 0.f, 0.f, 0.f};

        const int n4 = nact & ~3;
        const int G = n4 >> 2;            // full groups of 4 rows
        const int tc = nact - n4;         // tail rows (0..3)

        int4 I0, I1, I2, I3;
        float4 W0_0, W0_1, W0_2, W0_3;
        float4 W1_0, W1_1, W1_2, W1_3;
        float4 W2_0, W2_1, W2_2, W2_3;
        float4 W3_0, W3_1, W3_2, W3_3;

        // prologue: fill up to 4 stages + tail rows (all issued before any wait)
        if (0 < G) ISSUE(0, 0);
        if (1 < G) ISSUE(1, 1);
        if (2 < G) ISSUE(2, 2);
        if (3 < G) ISSUE(3, 3);
        float4 tw0, tw1, tw2;
        if (tc > 0) {
            const float* p = h2h + (size_t)__builtin_amdgcn_readfirstlane(list[hb][n4]) * NH;
            tw0 = *reinterpret_cast<const float4*>(p + n0);
        }
        if (tc > 1) {
            const float* p = h2h + (size_t)__builtin_amdgcn_readfirstlane(list[hb][n4 + 1]) * NH;
            tw1 = *reinterpret_cast<const float4*>(p + n0);
        }
        if (tc > 2) {
            const float* p = h2h + (size_t)__builtin_amdgcn_readfirstlane(list[hb][n4 + 2]) * NH;
            tw2 = *reinterpret_cast<const float4*>(p + n0);
        }

        // steady state: consume 4 stages, refill 4 stages (indices read first)
        int g = 0;
        for (; g + 4 <= G; g += 4) {
            const bool r0 = (g + 4 < G), r1 = (g + 5 < G), r2 = (g + 6 < G), r3 = (g + 7 < G);
            ACC(0); if (r0) ISSUE(0, g + 4);
            ACC(1); if (r1) ISSUE(1, g + 5);
            ACC(2); if (r2) ISSUE(2, g + 6);
            ACC(3); if (r3) ISSUE(3, g + 7);
        }
        // drain remaining issued stages (G - g in 0..3)
        if (g + 0 < G) ACC(0);
        if (g + 1 < G) ACC(1);
        if (g + 2 < G) ACC(2);
        // tail rows fold into a0, in list order (bit-exact vs old scalar tail)
        if (tc > 0) { a0[0] += tw0.x; a0[1] += tw0.y; a0[2] += tw0.z; a0[3] += tw0.w; }
        if (tc > 1) { a0[0] += tw1.x; a0[1] += tw1.y; a0[2] += tw1.z; a0[3] += tw1.w; }
        if (tc > 2) { a0[0] += tw2.x; a0[1] += tw2.y; a0[2] += tw2.z; a0[3] += tw2.w; }

        float ic[4];
        if (USE_XIN) {
            const float xiv[4] = {xi.x, xi.y, xi.z, xi.w};
            #pragma unroll
            for (int c = 0; c < 4; ++c) {
                const float rec = (a0[c] + a1[c]) + (a2[c] + a3[c]);
                ic[c] = (xiv[c] + rec) + bs[c];
            }
        } else {
            float m[4] = {0.f, 0.f, 0.f, 0.f};
            for (int i = 0; i < NI; ++i) {
                const float xv = xt[hb][i];
                const float4 w = *reinterpret_cast<const float4*>(&x2h[(size_t)i * NH + n0]);
                m[0] += xv * w.x; m[1] += xv * w.y; m[2] += xv * w.z; m[3] += xv * w.w;
            }
            #pragma unroll
            for (int c = 0; c < 4; ++c) {
                const float rec = (a0[c] + a1[c]) + (a2[c] + a3[c]);
                ic[c] = (m[c] + rec) + bs[c];
            }
        }

        // ---- LIF + RF oscillator (same expressions/order as previous kernel)
        float s[4];
        #pragma unroll
        for (int c = 0; c < 4; ++c) {
            lv[c] = lv[c] + DT * (-lv[c] / TAU_M + ic[c]);
            const float ls = lv[c] > 1.0f ? 1.0f : 0.0f;
            lv[c] -= ls;
            hz[c] = hz[c] + DT * ((GAIN * ls - GGAMMA * hy[c]) - GEPS * hz[c]);
            hy[c] = hy[c] + DT * hz[c];
            s[c] = ((hy[c] - 1.0f) - rf[c]) > 0.0f ? 1.0f : 0.0f;
            rf[c] = rf[c] * ref_decay + s[c];
            cnt[c] += s[c];
        }

        // ---- compaction ballots (deterministic, order-preserving; per half)
        const unsigned long long ba = __ballot(s[0] > 0.0f);
        const unsigned long long bb = __ballot(s[1] > 0.0f);
        const unsigned long long bc = __ballot(s[2] > 0.0f);
        const unsigned long long bd = __ballot(s[3] > 0.0f);
        if (lane == 0)
            wcnt[hb][wv] = (int)(__popcll(ba) + __popcll(bb) + __popcll(bc) + __popcll(bd));

        // ---- chunk boundary: commit next chunk (P, loaded 4 steps ago -> no
        // stall) into the other buffer; issue loads for the chunk after that.
        if (USE_XIN && ((t & 3) == 3)) {
            const int bufW = ((t >> 2) + 1) & 1;
            *reinterpret_cast<float4*>(&xstage[hb][bufW][0][n0]) = P0;
            *reinterpret_cast<float4*>(&xstage[hb][bufW][1][n0]) = P1;
            *reinterpret_cast<float4*>(&xstage[hb][bufW][2][n0]) = P2;
            *reinterpret_cast<float4*>(&xstage[hb][bufW][3][n0]) = P3;
            const int cNext = (t >> 2) + 2;
            if (cNext * 4 + 3 < T) {
                P0 = *reinterpret_cast<const float4*>(xrow + (size_t)(cNext * 4 + 0) * NH);
                P1 = *reinterpret_cast<const float4*>(xrow + (size_t)(cNext * 4 + 1) * NH);
                P2 = *reinterpret_cast<const float4*>(xrow + (size_t)(cNext * 4 + 2) * NH);
                P3 = *reinterpret_cast<const float4*>(xrow + (size_t)(cNext * 4 + 3) * NH);
            }
        }
        __syncthreads();   // list reads done; wcnt + staged xin visible

        // ---- phase 2: cross-wave exclusive prefix (2 x int4 LDS reads)
        const int4 c0 = *reinterpret_cast<const int4*>(&wcnt[hb][0]);
        const int4 c1 = *reinterpret_cast<const int4*>(&wcnt[hb][4]);
        int pre = 0;
        pre += (wv > 0) ? c0.x : 0;
        pre += (wv > 1) ? c0.y : 0;
        pre += (wv > 2) ? c0.z : 0;
        pre += (wv > 3) ? c0.w : 0;
        pre += (wv > 4) ? c1.x : 0;
        pre += (wv > 5) ? c1.y : 0;
        pre += (wv > 6) ? c1.z : 0;
        const int tot = ((c0.x + c0.y) + (c0.z + c0.w)) + ((c1.x + c1.y) + (c1.z + c1.w));

        const int gaLo = (int)__popcll(ba & lo32);
        const int gbLo = (int)__popcll(bb & lo32);
        const int gcLo = (int)__popcll(bc & lo32);
        const int gdLo = (int)__popcll(bd & lo32);
        const int g0 = gaLo + gcLo;                                   // comps{0,2} lanes<32
        const int g1 = gbLo + gdLo;                                   // comps{1,3} lanes<32
        const int g2 = (int)(__popcll(ba) + __popcll(bc)) - g0;       // comps{0,2} lanes>=32
        const int base02 = (lane < 32) ? 0 : (g0 + g1);
        const int base13 = (lane < 32) ? g0 : ((g0 + g1) + g2);
        const int pa = (int)__popcll(ba & mb);
        const int pb = (int)__popcll(bb & mb);
        const int pc = (int)__popcll(bc & mb);
        const int pd = (int)__popcll(bd & mb);
        const int o02 = pre + base02 + pa + pc;
        const int o13 = pre + base13 + pb + pd;
        if (s[0] > 0.0f) list[hb][o02] = n0;
        if (s[2] > 0.0f) list[hb][o02 + (int)((ba >> lane) & 1ull)] = n0 + 2;
        if (s[1] > 0.0f) list[hb][o13] = n0 + 1;
        if (s[3] > 0.0f) list[hb][o13 + (int)((bb >> lane) & 1ull)] = n0 + 3;
        nact = tot;
        if (!USE_XIN) {
            if (t + 1 < T && tl < NI) xt[hb][tl] = x[((size_t)b * T + (t + 1)) * NI + tl];
        }
        __syncthreads();   // list visible for next step
    }
#undef ISSUE
#undef ACC

    float4 o;
    o.x = cnt[0] / (float)T;
    o.y = cnt[1] / (float)T;
    o.z = cnt[2] / (float)T;
    o.w = cnt[3] / (float)T;
    *reinterpret_cast<float4*>(out + (size_t)b * NH + n0) = o;
}

extern "C" void kernel_launch(void* const* d_in, const int* in_sizes, int n_in,
                              void* d_out, int out_size, void* d_ws, size_t ws_size,
                              hipStream_t stream) {
    const float* x    = (const float*)d_in[0];   // [B,T,96]
    const float* x2h  = (const float*)d_in[1];   // [96,2048]
    const float* h2h  = (const float*)d_in[2];   // [2048,2048]
    const float* bias = (const float*)d_in[3];   // [2048]
    float* out = (float*)d_out;

    const int M = in_sizes[0] / NI;   // B*T
    const int T = 1024;
    const int B = M / T;

    const size_t xin_bytes = (size_t)M * NH * sizeof(float);
    if (ws_size >= xin_bytes) {
        float* xin = (float*)d_ws;
        dim3 grid(NH / 64, M / 64);
        xin_gemm<<<grid, 256, 0, stream>>>(x, x2h, xin);
        if ((B & 1) == 0 && B >= 2) {
            esn_seq<1, 2><<<B / 2, 1024, 0, stream>>>(xin, x, x2h, h2h, bias, out, T);
        } else {
            esn_seq<1, 1><<<B, 512, 0, stream>>>(xin, x, x2h, h2h, bias, out, T);
        }
    } else {
        if ((B & 1) == 0 && B >= 2) {
            esn_seq<0, 2><<<B / 2, 1024, 0, stream>>>(x /*unused*/, x, x2h, h2h, bias, out, T);
        } else {
            esn_seq<0, 1><<<B, 512, 0, stream>>>(x /*unused*/, x, x2h, h2h, bias, out, T);
        }
    }
}

// Round 6
// 11495.309 us; speedup vs baseline: 1.0006x; 1.0006x over previous
//
#include <hip/hip_runtime.h>
#include <cmath>

#define NH 2048
#define NI 96

// ---------------- GEMM: xin[b,t,:] = x[b,t,:] @ x2h  (no bias; bias added in seq kernel
// to match reference association order (xmul + smul) + bias) ----------------
__global__ __launch_bounds__(256) void xin_gemm(
    const float* __restrict__ A,
    const float* __restrict__ Bm,
    float* __restrict__ C)
{
    __shared__ float At[96][68];  // transposed A tile: At[k][r]
    __shared__ float Bt[96][68];  // Bt[k][c]
    const int tid = threadIdx.x;
    const int rowBase = blockIdx.y * 64;
    const int colBase = blockIdx.x * 64;

    {
        const int r = tid >> 2;
        const int sub = tid & 3;
        const float4* Arow = reinterpret_cast<const float4*>(A + (size_t)(rowBase + r) * NI);
        #pragma unroll
        for (int q = 0; q < 6; ++q) {
            const int k4 = sub + 4 * q;      // 0..23
            float4 v = Arow[k4];
            At[k4 * 4 + 0][r] = v.x;
            At[k4 * 4 + 1][r] = v.y;
            At[k4 * 4 + 2][r] = v.z;
            At[k4 * 4 + 3][r] = v.w;
        }
    }
    {
        const int c4 = tid & 15;
        const int k0 = tid >> 4;
        #pragma unroll
        for (int g = 0; g < 6; ++g) {
            const int kk = k0 + 16 * g;      // 0..95
            float4 v = *reinterpret_cast<const float4*>(Bm + (size_t)kk * NH + colBase + c4 * 4);
            *reinterpret_cast<float4*>(&Bt[kk][c4 * 4]) = v;
        }
    }
    __syncthreads();

    const int ty = tid >> 4, tx = tid & 15;
    float acc[4][4] = {};
    #pragma unroll 8
    for (int kk = 0; kk < 96; ++kk) {
        float4 a = *reinterpret_cast<const float4*>(&At[kk][ty * 4]);
        float4 b = *reinterpret_cast<const float4*>(&Bt[kk][tx * 4]);
        acc[0][0] += a.x * b.x; acc[0][1] += a.x * b.y; acc[0][2] += a.x * b.z; acc[0][3] += a.x * b.w;
        acc[1][0] += a.y * b.x; acc[1][1] += a.y * b.y; acc[1][2] += a.y * b.z; acc[1][3] += a.y * b.w;
        acc[2][0] += a.z * b.x; acc[2][1] += a.z * b.y; acc[2][2] += a.z * b.z; acc[2][3] += a.z * b.w;
        acc[3][0] += a.w * b.x; acc[3][1] += a.w * b.y; acc[3][2] += a.w * b.z; acc[3][3] += a.w * b.w;
    }
    #pragma unroll
    for (int i = 0; i < 4; ++i) {
        float4 o;
        o.x = acc[i][0]; o.y = acc[i][1]; o.z = acc[i][2]; o.w = acc[i][3];
        *reinterpret_cast<float4*>(C + (size_t)(rowBase + ty * 4 + i) * NH + colBase + tx * 4) = o;
    }
}

// ---------------- Sequential recurrence ----------------
// NB batches per block (NB=2: 1024 threads, threads 0-511 = batch 2i,
// 512-1023 = batch 2i+1; each half has its OWN list/wcnt/xstage, so the
// per-batch code path and arithmetic order are IDENTICAL to the NB=1 kernel
// -> bit-exact). Co-locating two independent recurrences on one CU gives
// 4 waves/SIMD from 2 independent dependency chains: one half's LLC-latency
// gather stall is overlapped by the other half's loads + VALU work, and the
// two barriers per step are amortized over 2 batches. LDS 148 KB forces
// 1 block/CU (the co-location we want).
// __launch_bounds__ second arg = min waves per EU: 4 waves/SIMD = 16 waves/CU
// = exactly 1 block/CU -> VGPR cap 128 (R5's default capped at 64 and spilled
// the whole pipeline to scratch: VGPR 64, WRITE_SIZE 6.4 MB, 10x regression).
// Per half: 512 threads; thread owns 4 neurons n0=4*tl .. n0+3. xin staged
// through LDS in 4-step chunks (double-buffered); gather row indices
// readfirstlane'd to SGPR base (saddr loads); 4-stage rotated load pipeline.
// Accumulation order: row at list position k -> a[k%4] for k<n4, tail rows
// fold into a0 in list order; reduce tree unchanged.
template <int USE_XIN, int NB>
__global__ __launch_bounds__(NB * 512, NB == 2 ? 4 : 2) void esn_seq(
    const float* __restrict__ xin,   // [B*T*NH] (xmul only) if USE_XIN
    const float* __restrict__ x,     // [B*T*NI] for fallback
    const float* __restrict__ x2h,   // [NI*NH]
    const float* __restrict__ h2h,   // [NH*NH]
    const float* __restrict__ bias,  // [NH]
    float* __restrict__ out,         // [B*NH]
    int T)
{
    const int tid = threadIdx.x;
    const int hb = (NB == 2) ? (tid >> 9) : 0;     // which half/batch
    const int tl = (NB == 2) ? (tid & 511) : tid;  // thread-in-half
    const int b = blockIdx.x * NB + hb;
    const int n0 = tl * 4;
    const int wv = tl >> 6;          // wave within half (0..7)
    const int lane = tid & 63;

    __shared__ alignas(16) int list[NB][NH];
    __shared__ alignas(16) int wcnt[NB][8];
    __shared__ float xt[NB][NI];
    __shared__ alignas(16) float xstage[NB][2][4][NH];  // per half: 2 bufs x 4 steps

    constexpr float DT = 0.075f;
    constexpr float TAU_M = 0.5f;
    constexpr float GGAMMA = 2.7f;
    constexpr float GEPS = 4.7f;
    constexpr float GAIN = 5.0f;
    const float ref_decay = expf(-0.075f / 0.25f);

    float lv[4] = {0.f, 0.f, 0.f, 0.f};
    float hy[4] = {0.f, 0.f, 0.f, 0.f};
    float hz[4] = {0.f, 0.f, 0.f, 0.f};
    float rf[4] = {0.f, 0.f, 0.f, 0.f};
    float cnt[4] = {0.f, 0.f, 0.f, 0.f};
    float bs[4];
    {
        const float4 b4 = *reinterpret_cast<const float4*>(&bias[n0]);
        bs[0] = b4.x; bs[1] = b4.y; bs[2] = b4.z; bs[3] = b4.w;
    }
    int nact = 0;

    const float* __restrict__ xrow = USE_XIN ? (xin + (size_t)b * T * NH + n0) : xin;

    // chunk-staging registers: hold the NEXT chunk (4 rows) of this thread's
    // 4 xin columns; written to LDS at the next boundary.
    float4 P0, P1, P2, P3;

    if (USE_XIN) {
        #pragma unroll
        for (int r = 0; r < 4; ++r) {
            float4 v = *reinterpret_cast<const float4*>(xrow + (size_t)r * NH);
            *reinterpret_cast<float4*>(&xstage[hb][0][r][n0]) = v;
        }
        P0 = *reinterpret_cast<const float4*>(xrow + (size_t)4 * NH);
        P1 = *reinterpret_cast<const float4*>(xrow + (size_t)5 * NH);
        P2 = *reinterpret_cast<const float4*>(xrow + (size_t)6 * NH);
        P3 = *reinterpret_cast<const float4*>(xrow + (size_t)7 * NH);
    } else {
        if (tl < NI) xt[hb][tl] = x[(size_t)b * T * NI + tl];
    }
    __syncthreads();

    const unsigned long long below = (1ull << lane) - 1ull;
    const unsigned long long lo32 = 0xFFFFFFFFull;
    const unsigned long long mb = (lane >= 32) ? (below & ~lo32) : below;

    const int4* __restrict__ L4 = reinterpret_cast<const int4*>(&list[hb][0]);

// pipeline stage macros: ISSUE reads 1 int4 of indices (half-uniform ->
// readfirstlane to SGPR base) + 4 h2h rows (float4 each); ACC folds the stage
// into accumulators with the fixed pos%4 -> a{0..3} mapping.
#define ISSUE(St, grp) do {                                                              \
        I##St = L4[(grp)];                                                               \
        const float* pr0 = h2h + (size_t)__builtin_amdgcn_readfirstlane(I##St.x) * NH;   \
        const float* pr1 = h2h + (size_t)__builtin_amdgcn_readfirstlane(I##St.y) * NH;   \
        const float* pr2 = h2h + (size_t)__builtin_amdgcn_readfirstlane(I##St.z) * NH;   \
        const float* pr3 = h2h + (size_t)__builtin_amdgcn_readfirstlane(I##St.w) * NH;   \
        W##St##_0 = *reinterpret_cast<const float4*>(pr0 + n0);                          \
        W##St##_1 = *reinterpret_cast<const float4*>(pr1 + n0);                          \
        W##St##_2 = *reinterpret_cast<const float4*>(pr2 + n0);                          \
        W##St##_3 = *reinterpret_cast<const float4*>(pr3 + n0);                          \
    } while (0)
#define ACC(St) do {                                                                  \
        a0[0] += W##St##_0.x; a0[1] += W##St##_0.y; a0[2] += W##St##_0.z; a0[3] += W##St##_0.w; \
        a1[0] += W##St##_1.x; a1[1] += W##St##_1.y; a1[2] += W##St##_1.z; a1[3] += W##St##_1.w; \
        a2[0] += W##St##_2.x; a2[1] += W##St##_2.y; a2[2] += W##St##_2.z; a2[3] += W##St##_2.w; \
        a3[0] += W##St##_3.x; a3[1] += W##St##_3.y; a3[2] += W##St##_3.z; a3[3] += W##St##_3.w; \
    } while (0)

    for (int t = 0; t < T; ++t) {
        // ---- current step's xin row: LDS read, hidden under the gather.
        float4 xi;
        if (USE_XIN) xi = *reinterpret_cast<const float4*>(&xstage[hb][(t >> 2) & 1][t & 3][n0]);

        // ---- phase 1: pipelined gather over active rows (prev step's s)
        float a0[4] = {0.f, 0.f, 0.f, 0.f};
        float a1[4] = {0.f, 0.f, 0.f, 0.f};
        float a2[4] = {0.f, 0.f, 0.f, 0.f};
        float a3[4] = {0.f, 0.f, 0.f, 0.f};

        const int n4 = nact & ~3;
        const int G = n4 >> 2;            // full groups of 4 rows
        const int tc = nact - n4;         // tail rows (0..3)

        int4 I0, I1, I2, I3;
        float4 W0_0, W0_1, W0_2, W0_3;
        float4 W1_0, W1_1, W1_2, W1_3;
        float4 W2_0, W2_1, W2_2, W2_3;
        float4 W3_0, W3_1, W3_2, W3_3;

        // prologue: fill up to 4 stages + tail rows (all issued before any wait)
        if (0 < G) ISSUE(0, 0);
        if (1 < G) ISSUE(1, 1);
        if (2 < G) ISSUE(2, 2);
        if (3 < G) ISSUE(3, 3);
        float4 tw0, tw1, tw2;
        if (tc > 0) {
            const float* p = h2h + (size_t)__builtin_amdgcn_readfirstlane(list[hb][n4]) * NH;
            tw0 = *reinterpret_cast<const float4*>(p + n0);
        }
        if (tc > 1) {
            const float* p = h2h + (size_t)__builtin_amdgcn_readfirstlane(list[hb][n4 + 1]) * NH;
            tw1 = *reinterpret_cast<const float4*>(p + n0);
        }
        if (tc > 2) {
            const float* p = h2h + (size_t)__builtin_amdgcn_readfirstlane(list[hb][n4 + 2]) * NH;
            tw2 = *reinterpret_cast<const float4*>(p + n0);
        }

        // steady state: consume 4 stages, refill 4 stages (indices read first)
        int g = 0;
        for (; g + 4 <= G; g += 4) {
            const bool r0 = (g + 4 < G), r1 = (g + 5 < G), r2 = (g + 6 < G), r3 = (g + 7 < G);
            ACC(0); if (r0) ISSUE(0, g + 4);
            ACC(1); if (r1) ISSUE(1, g + 5);
            ACC(2); if (r2) ISSUE(2, g + 6);
            ACC(3); if (r3) ISSUE(3, g + 7);
        }
        // drain remaining issued stages (G - g in 0..3)
        if (g + 0 < G) ACC(0);
        if (g + 1 < G) ACC(1);
        if (g + 2 < G) ACC(2);
        // tail rows fold into a0, in list order (bit-exact vs old scalar tail)
        if (tc > 0) { a0[0] += tw0.x; a0[1] += tw0.y; a0[2] += tw0.z; a0[3] += tw0.w; }
        if (tc > 1) { a0[0] += tw1.x; a0[1] += tw1.y; a0[2] += tw1.z; a0[3] += tw1.w; }
        if (tc > 2) { a0[0] += tw2.x; a0[1] += tw2.y; a0[2] += tw2.z; a0[3] += tw2.w; }

        float ic[4];
        if (USE_XIN) {
            const float xiv[4] = {xi.x, xi.y, xi.z, xi.w};
            #pragma unroll
            for (int c = 0; c < 4; ++c) {
                const float rec = (a0[c] + a1[c]) + (a2[c] + a3[c]);
                ic[c] = (xiv[c] + rec) + bs[c];
            }
        } else {
            float m[4] = {0.f, 0.f, 0.f, 0.f};
            for (int i = 0; i < NI; ++i) {
                const float xv = xt[hb][i];
                const float4 w = *reinterpret_cast<const float4*>(&x2h[(size_t)i * NH + n0]);
                m[0] += xv * w.x; m[1] += xv * w.y; m[2] += xv * w.z; m[3] += xv * w.w;
            }
            #pragma unroll
            for (int c = 0; c < 4; ++c) {
                const float rec = (a0[c] + a1[c]) + (a2[c] + a3[c]);
                ic[c] = (m[c] + rec) + bs[c];
            }
        }

        // ---- LIF + RF oscillator (same expressions/order as previous kernel)
        float s[4];
        #pragma unroll
        for (int c = 0; c < 4; ++c) {
            lv[c] = lv[c] + DT * (-lv[c] / TAU_M + ic[c]);
            const float ls = lv[c] > 1.0f ? 1.0f : 0.0f;
            lv[c] -= ls;
            hz[c] = hz[c] + DT * ((GAIN * ls - GGAMMA * hy[c]) - GEPS * hz[c]);
            hy[c] = hy[c] + DT * hz[c];
            s[c] = ((hy[c] - 1.0f) - rf[c]) > 0.0f ? 1.0f : 0.0f;
            rf[c] = rf[c] * ref_decay + s[c];
            cnt[c] += s[c];
        }

        // ---- compaction ballots (deterministic, order-preserving; per half)
        const unsigned long long ba = __ballot(s[0] > 0.0f);
        const unsigned long long bb = __ballot(s[1] > 0.0f);
        const unsigned long long bc = __ballot(s[2] > 0.0f);
        const unsigned long long bd = __ballot(s[3] > 0.0f);
        if (lane == 0)
            wcnt[hb][wv] = (int)(__popcll(ba) + __popcll(bb) + __popcll(bc) + __popcll(bd));

        // ---- chunk boundary: commit next chunk (P, loaded 4 steps ago -> no
        // stall) into the other buffer; issue loads for the chunk after that.
        if (USE_XIN && ((t & 3) == 3)) {
            const int bufW = ((t >> 2) + 1) & 1;
            *reinterpret_cast<float4*>(&xstage[hb][bufW][0][n0]) = P0;
            *reinterpret_cast<float4*>(&xstage[hb][bufW][1][n0]) = P1;
            *reinterpret_cast<float4*>(&xstage[hb][bufW][2][n0]) = P2;
            *reinterpret_cast<float4*>(&xstage[hb][bufW][3][n0]) = P3;
            const int cNext = (t >> 2) + 2;
            if (cNext * 4 + 3 < T) {
                P0 = *reinterpret_cast<const float4*>(xrow + (size_t)(cNext * 4 + 0) * NH);
                P1 = *reinterpret_cast<const float4*>(xrow + (size_t)(cNext * 4 + 1) * NH);
                P2 = *reinterpret_cast<const float4*>(xrow + (size_t)(cNext * 4 + 2) * NH);
                P3 = *reinterpret_cast<const float4*>(xrow + (size_t)(cNext * 4 + 3) * NH);
            }
        }
        __syncthreads();   // list reads done; wcnt + staged xin visible

        // ---- phase 2: cross-wave exclusive prefix (2 x int4 LDS reads)
        const int4 c0 = *reinterpret_cast<const int4*>(&wcnt[hb][0]);
        const int4 c1 = *reinterpret_cast<const int4*>(&wcnt[hb][4]);
        int pre = 0;
        pre += (wv > 0) ? c0.x : 0;
        pre += (wv > 1) ? c0.y : 0;
        pre += (wv > 2) ? c0.z : 0;
        pre += (wv > 3) ? c0.w : 0;
        pre += (wv > 4) ? c1.x : 0;
        pre += (wv > 5) ? c1.y : 0;
        pre += (wv > 6) ? c1.z : 0;
        const int tot = ((c0.x + c0.y) + (c0.z + c0.w)) + ((c1.x + c1.y) + (c1.z + c1.w));

        const int gaLo = (int)__popcll(ba & lo32);
        const int gbLo = (int)__popcll(bb & lo32);
        const int gcLo = (int)__popcll(bc & lo32);
        const int gdLo = (int)__popcll(bd & lo32);
        const int g0 = gaLo + gcLo;                                   // comps{0,2} lanes<32
        const int g1 = gbLo + gdLo;                                   // comps{1,3} lanes<32
        const int g2 = (int)(__popcll(ba) + __popcll(bc)) - g0;       // comps{0,2} lanes>=32
        const int base02 = (lane < 32) ? 0 : (g0 + g1);
        const int base13 = (lane < 32) ? g0 : ((g0 + g1) + g2);
        const int pa = (int)__popcll(ba & mb);
        const int pb = (int)__popcll(bb & mb);
        const int pc = (int)__popcll(bc & mb);
        const int pd = (int)__popcll(bd & mb);
        const int o02 = pre + base02 + pa + pc;
        const int o13 = pre + base13 + pb + pd;
        if (s[0] > 0.0f) list[hb][o02] = n0;
        if (s[2] > 0.0f) list[hb][o02 + (int)((ba >> lane) & 1ull)] = n0 + 2;
        if (s[1] > 0.0f) list[hb][o13] = n0 + 1;
        if (s[3] > 0.0f) list[hb][o13 + (int)((bb >> lane) & 1ull)] = n0 + 3;
        nact = tot;
        if (!USE_XIN) {
            if (t + 1 < T && tl < NI) xt[hb][tl] = x[((size_t)b * T + (t + 1)) * NI + tl];
        }
        __syncthreads();   // list visible for next step
    }
#undef ISSUE
#undef ACC

    float4 o;
    o.x = cnt[0] / (float)T;
    o.y = cnt[1] / (float)T;
    o.z = cnt[2] / (float)T;
    o.w = cnt[3] / (float)T;
    *reinterpret_cast<float4*>(out + (size_t)b * NH + n0) = o;
}

extern "C" void kernel_launch(void* const* d_in, const int* in_sizes, int n_in,
                              void* d_out, int out_size, void* d_ws, size_t ws_size,
                              hipStream_t stream) {
    const float* x    = (const float*)d_in[0];   // [B,T,96]
    const float* x2h  = (const float*)d_in[1];   // [96,2048]
    const float* h2h  = (const float*)d_in[2];   // [2048,2048]
    const float* bias = (const float*)d_in[3];   // [2048]
    float* out = (float*)d_out;

    const int M = in_sizes[0] / NI;   // B*T
    const int T = 1024;
    const int B = M / T;

    const size_t xin_bytes = (size_t)M * NH * sizeof(float);
    if (ws_size >= xin_bytes) {
        float* xin = (float*)d_ws;
        dim3 grid(NH / 64, M / 64);
        xin_gemm<<<grid, 256, 0, stream>>>(x, x2h, xin);
        if ((B & 1) == 0 && B >= 2) {
            esn_seq<1, 2><<<B / 2, 1024, 0, stream>>>(xin, x, x2h, h2h, bias, out, T);
        } else {
            esn_seq<1, 1><<<B, 512, 0, stream>>>(xin, x, x2h, h2h, bias, out, T);
        }
    } else {
        if ((B & 1) == 0 && B >= 2) {
            esn_seq<0, 2><<<B / 2, 1024, 0, stream>>>(x /*unused*/, x, x2h, h2h, bias, out, T);
        } else {
            esn_seq<0, 1><<<B, 512, 0, stream>>>(x /*unused*/, x, x2h, h2h, bias, out, T);
        }
    }
}

// Round 7
// 11423.064 us; speedup vs baseline: 1.0069x; 1.0063x over previous
//
#include <hip/hip_runtime.h>
#include <cmath>

#define NH 2048
#define NI 96

// ---------------- GEMM: xin[b,t,:] = x[b,t,:] @ x2h  (no bias; bias added in seq kernel
// to match reference association order (xmul + smul) + bias) ----------------
__global__ __launch_bounds__(256) void xin_gemm(
    const float* __restrict__ A,
    const float* __restrict__ Bm,
    float* __restrict__ C)
{
    __shared__ float At[96][68];  // transposed A tile: At[k][r]
    __shared__ float Bt[96][68];  // Bt[k][c]
    const int tid = threadIdx.x;
    const int rowBase = blockIdx.y * 64;
    const int colBase = blockIdx.x * 64;

    {
        const int r = tid >> 2;
        const int sub = tid & 3;
        const float4* Arow = reinterpret_cast<const float4*>(A + (size_t)(rowBase + r) * NI);
        #pragma unroll
        for (int q = 0; q < 6; ++q) {
            const int k4 = sub + 4 * q;      // 0..23
            float4 v = Arow[k4];
            At[k4 * 4 + 0][r] = v.x;
            At[k4 * 4 + 1][r] = v.y;
            At[k4 * 4 + 2][r] = v.z;
            At[k4 * 4 + 3][r] = v.w;
        }
    }
    {
        const int c4 = tid & 15;
        const int k0 = tid >> 4;
        #pragma unroll
        for (int g = 0; g < 6; ++g) {
            const int kk = k0 + 16 * g;      // 0..95
            float4 v = *reinterpret_cast<const float4*>(Bm + (size_t)kk * NH + colBase + c4 * 4);
            *reinterpret_cast<float4*>(&Bt[kk][c4 * 4]) = v;
        }
    }
    __syncthreads();

    const int ty = tid >> 4, tx = tid & 15;
    float acc[4][4] = {};
    #pragma unroll 8
    for (int kk = 0; kk < 96; ++kk) {
        float4 a = *reinterpret_cast<const float4*>(&At[kk][ty * 4]);
        float4 b = *reinterpret_cast<const float4*>(&Bt[kk][tx * 4]);
        acc[0][0] += a.x * b.x; acc[0][1] += a.x * b.y; acc[0][2] += a.x * b.z; acc[0][3] += a.x * b.w;
        acc[1][0] += a.y * b.x; acc[1][1] += a.y * b.y; acc[1][2] += a.y * b.z; acc[1][3] += a.y * b.w;
        acc[2][0] += a.z * b.x; acc[2][1] += a.z * b.y; acc[2][2] += a.z * b.z; acc[2][3] += a.z * b.w;
        acc[3][0] += a.w * b.x; acc[3][1] += a.w * b.y; acc[3][2] += a.w * b.z; acc[3][3] += a.w * b.w;
    }
    #pragma unroll
    for (int i = 0; i < 4; ++i) {
        float4 o;
        o.x = acc[i][0]; o.y = acc[i][1]; o.z = acc[i][2]; o.w = acc[i][3];
        *reinterpret_cast<float4*>(C + (size_t)(rowBase + ty * 4 + i) * NH + colBase + tx * 4) = o;
    }
}

// ---------------- Sequential recurrence (shared body) ----------------
// NB batches per block (NB=2: 1024 threads, threads 0-511 = batch 2i,
// 512-1023 = batch 2i+1; each half has its OWN list/wcnt/xstage, so the
// per-batch code path and arithmetic order are IDENTICAL to the NB=1 kernel
// -> bit-exact). Co-locating two independent recurrences on one CU gives
// 4 waves/SIMD from 2 independent dependency chains.
// NOTE on codegen (R5/R6 lesson): the launch-bounds SECOND arg with a
// template-dependent expression was SILENTLY DROPPED -> compiler capped VGPR
// at 64 (8 waves/EU target) and spilled the whole pipeline to scratch
// (WRITE_SIZE 256KB -> 6.4MB, 10x regression). Fix: non-dependent literal
// attributes on thin wrappers; NB=2 uses amdgpu_waves_per_eu(4,4) to pin
// waves/EU = 4 -> VGPR budget 128 >= the 116 the body needs.
template <int USE_XIN, int NB>
__device__ __forceinline__ void esn_body(
    const float* __restrict__ xin,   // [B*T*NH] (xmul only) if USE_XIN
    const float* __restrict__ x,     // [B*T*NI] for fallback
    const float* __restrict__ x2h,   // [NI*NH]
    const float* __restrict__ h2h,   // [NH*NH]
    const float* __restrict__ bias,  // [NH]
    float* __restrict__ out,         // [B*NH]
    int T)
{
    const int tid = threadIdx.x;
    const int hb = (NB == 2) ? (tid >> 9) : 0;     // which half/batch
    const int tl = (NB == 2) ? (tid & 511) : tid;  // thread-in-half
    const int b = blockIdx.x * NB + hb;
    const int n0 = tl * 4;
    const int wv = tl >> 6;          // wave within half (0..7)
    const int lane = tid & 63;

    __shared__ alignas(16) int list[NB][NH];
    __shared__ alignas(16) int wcnt[NB][8];
    __shared__ float xt[NB][NI];
    __shared__ alignas(16) float xstage[NB][2][4][NH];  // per half: 2 bufs x 4 steps

    constexpr float DT = 0.075f;
    constexpr float TAU_M = 0.5f;
    constexpr float GGAMMA = 2.7f;
    constexpr float GEPS = 4.7f;
    constexpr float GAIN = 5.0f;
    const float ref_decay = expf(-0.075f / 0.25f);

    float lv[4] = {0.f, 0.f, 0.f, 0.f};
    float hy[4] = {0.f, 0.f, 0.f, 0.f};
    float hz[4] = {0.f, 0.f, 0.f, 0.f};
    float rf[4] = {0.f, 0.f, 0.f, 0.f};
    float cnt[4] = {0.f, 0.f, 0.f, 0.f};
    float bs[4];
    {
        const float4 b4 = *reinterpret_cast<const float4*>(&bias[n0]);
        bs[0] = b4.x; bs[1] = b4.y; bs[2] = b4.z; bs[3] = b4.w;
    }
    int nact = 0;

    const float* __restrict__ xrow = USE_XIN ? (xin + (size_t)b * T * NH + n0) : xin;

    // chunk-staging registers: hold the NEXT chunk (4 rows) of this thread's
    // 4 xin columns; written to LDS at the next boundary.
    float4 P0, P1, P2, P3;

    if (USE_XIN) {
        #pragma unroll
        for (int r = 0; r < 4; ++r) {
            float4 v = *reinterpret_cast<const float4*>(xrow + (size_t)r * NH);
            *reinterpret_cast<float4*>(&xstage[hb][0][r][n0]) = v;
        }
        P0 = *reinterpret_cast<const float4*>(xrow + (size_t)4 * NH);
        P1 = *reinterpret_cast<const float4*>(xrow + (size_t)5 * NH);
        P2 = *reinterpret_cast<const float4*>(xrow + (size_t)6 * NH);
        P3 = *reinterpret_cast<const float4*>(xrow + (size_t)7 * NH);
    } else {
        if (tl < NI) xt[hb][tl] = x[(size_t)b * T * NI + tl];
    }
    __syncthreads();

    const unsigned long long below = (1ull << lane) - 1ull;
    const unsigned long long lo32 = 0xFFFFFFFFull;
    const unsigned long long mb = (lane >= 32) ? (below & ~lo32) : below;

    const int4* __restrict__ L4 = reinterpret_cast<const int4*>(&list[hb][0]);

// pipeline stage macros: ISSUE reads 1 int4 of indices (half-uniform ->
// readfirstlane to SGPR base) + 4 h2h rows (float4 each); ACC folds the stage
// into accumulators with the fixed pos%4 -> a{0..3} mapping.
#define ISSUE(St, grp) do {                                                              \
        I##St = L4[(grp)];                                                               \
        const float* pr0 = h2h + (size_t)__builtin_amdgcn_readfirstlane(I##St.x) * NH;   \
        const float* pr1 = h2h + (size_t)__builtin_amdgcn_readfirstlane(I##St.y) * NH;   \
        const float* pr2 = h2h + (size_t)__builtin_amdgcn_readfirstlane(I##St.z) * NH;   \
        const float* pr3 = h2h + (size_t)__builtin_amdgcn_readfirstlane(I##St.w) * NH;   \
        W##St##_0 = *reinterpret_cast<const float4*>(pr0 + n0);                          \
        W##St##_1 = *reinterpret_cast<const float4*>(pr1 + n0);                          \
        W##St##_2 = *reinterpret_cast<const float4*>(pr2 + n0);                          \
        W##St##_3 = *reinterpret_cast<const float4*>(pr3 + n0);                          \
    } while (0)
#define ACC(St) do {                                                                  \
        a0[0] += W##St##_0.x; a0[1] += W##St##_0.y; a0[2] += W##St##_0.z; a0[3] += W##St##_0.w; \
        a1[0] += W##St##_1.x; a1[1] += W##St##_1.y; a1[2] += W##St##_1.z; a1[3] += W##St##_1.w; \
        a2[0] += W##St##_2.x; a2[1] += W##St##_2.y; a2[2] += W##St##_2.z; a2[3] += W##St##_2.w; \
        a3[0] += W##St##_3.x; a3[1] += W##St##_3.y; a3[2] += W##St##_3.z; a3[3] += W##St##_3.w; \
    } while (0)

    for (int t = 0; t < T; ++t) {
        // ---- current step's xin row: LDS read, hidden under the gather.
        float4 xi;
        if (USE_XIN) xi = *reinterpret_cast<const float4*>(&xstage[hb][(t >> 2) & 1][t & 3][n0]);

        // ---- phase 1: pipelined gather over active rows (prev step's s)
        float a0[4] = {0.f, 0.f, 0.f, 0.f};
        float a1[4] = {0.f, 0.f, 0.f, 0.f};
        float a2[4] = {0.f, 0.f, 0.f, 0.f};
        float a3[4] = {0.f, 0.f, 0.f, 0.f};

        const int n4 = nact & ~3;
        const int G = n4 >> 2;            // full groups of 4 rows
        const int tc = nact - n4;         // tail rows (0..3)

        int4 I0, I1, I2, I3;
        float4 W0_0, W0_1, W0_2, W0_3;
        float4 W1_0, W1_1, W1_2, W1_3;
        float4 W2_0, W2_1, W2_2, W2_3;
        float4 W3_0, W3_1, W3_2, W3_3;

        // prologue: fill up to 4 stages + tail rows (all issued before any wait)
        if (0 < G) ISSUE(0, 0);
        if (1 < G) ISSUE(1, 1);
        if (2 < G) ISSUE(2, 2);
        if (3 < G) ISSUE(3, 3);
        float4 tw0, tw1, tw2;
        if (tc > 0) {
            const float* p = h2h + (size_t)__builtin_amdgcn_readfirstlane(list[hb][n4]) * NH;
            tw0 = *reinterpret_cast<const float4*>(p + n0);
        }
        if (tc > 1) {
            const float* p = h2h + (size_t)__builtin_amdgcn_readfirstlane(list[hb][n4 + 1]) * NH;
            tw1 = *reinterpret_cast<const float4*>(p + n0);
        }
        if (tc > 2) {
            const float* p = h2h + (size_t)__builtin_amdgcn_readfirstlane(list[hb][n4 + 2]) * NH;
            tw2 = *reinterpret_cast<const float4*>(p + n0);
        }

        // steady state: consume 4 stages, refill 4 stages (indices read first)
        int g = 0;
        for (; g + 4 <= G; g += 4) {
            const bool r0 = (g + 4 < G), r1 = (g + 5 < G), r2 = (g + 6 < G), r3 = (g + 7 < G);
            ACC(0); if (r0) ISSUE(0, g + 4);
            ACC(1); if (r1) ISSUE(1, g + 5);
            ACC(2); if (r2) ISSUE(2, g + 6);
            ACC(3); if (r3) ISSUE(3, g + 7);
        }
        // drain remaining issued stages (G - g in 0..3)
        if (g + 0 < G) ACC(0);
        if (g + 1 < G) ACC(1);
        if (g + 2 < G) ACC(2);
        // tail rows fold into a0, in list order (bit-exact vs old scalar tail)
        if (tc > 0) { a0[0] += tw0.x; a0[1] += tw0.y; a0[2] += tw0.z; a0[3] += tw0.w; }
        if (tc > 1) { a0[0] += tw1.x; a0[1] += tw1.y; a0[2] += tw1.z; a0[3] += tw1.w; }
        if (tc > 2) { a0[0] += tw2.x; a0[1] += tw2.y; a0[2] += tw2.z; a0[3] += tw2.w; }

        float ic[4];
        if (USE_XIN) {
            const float xiv[4] = {xi.x, xi.y, xi.z, xi.w};
            #pragma unroll
            for (int c = 0; c < 4; ++c) {
                const float rec = (a0[c] + a1[c]) + (a2[c] + a3[c]);
                ic[c] = (xiv[c] + rec) + bs[c];
            }
        } else {
            float m[4] = {0.f, 0.f, 0.f, 0.f};
            for (int i = 0; i < NI; ++i) {
                const float xv = xt[hb][i];
                const float4 w = *reinterpret_cast<const float4*>(&x2h[(size_t)i * NH + n0]);
                m[0] += xv * w.x; m[1] += xv * w.y; m[2] += xv * w.z; m[3] += xv * w.w;
            }
            #pragma unroll
            for (int c = 0; c < 4; ++c) {
                const float rec = (a0[c] + a1[c]) + (a2[c] + a3[c]);
                ic[c] = (m[c] + rec) + bs[c];
            }
        }

        // ---- LIF + RF oscillator (same expressions/order as previous kernel)
        float s[4];
        #pragma unroll
        for (int c = 0; c < 4; ++c) {
            lv[c] = lv[c] + DT * (-lv[c] / TAU_M + ic[c]);
            const float ls = lv[c] > 1.0f ? 1.0f : 0.0f;
            lv[c] -= ls;
            hz[c] = hz[c] + DT * ((GAIN * ls - GGAMMA * hy[c]) - GEPS * hz[c]);
            hy[c] = hy[c] + DT * hz[c];
            s[c] = ((hy[c] - 1.0f) - rf[c]) > 0.0f ? 1.0f : 0.0f;
            rf[c] = rf[c] * ref_decay + s[c];
            cnt[c] += s[c];
        }

        // ---- compaction ballots (deterministic, order-preserving; per half)
        const unsigned long long ba = __ballot(s[0] > 0.0f);
        const unsigned long long bb = __ballot(s[1] > 0.0f);
        const unsigned long long bc = __ballot(s[2] > 0.0f);
        const unsigned long long bd = __ballot(s[3] > 0.0f);
        if (lane == 0)
            wcnt[hb][wv] = (int)(__popcll(ba) + __popcll(bb) + __popcll(bc) + __popcll(bd));

        // ---- chunk boundary: commit next chunk (P, loaded 4 steps ago -> no
        // stall) into the other buffer; issue loads for the chunk after that.
        if (USE_XIN && ((t & 3) == 3)) {
            const int bufW = ((t >> 2) + 1) & 1;
            *reinterpret_cast<float4*>(&xstage[hb][bufW][0][n0]) = P0;
            *reinterpret_cast<float4*>(&xstage[hb][bufW][1][n0]) = P1;
            *reinterpret_cast<float4*>(&xstage[hb][bufW][2][n0]) = P2;
            *reinterpret_cast<float4*>(&xstage[hb][bufW][3][n0]) = P3;
            const int cNext = (t >> 2) + 2;
            if (cNext * 4 + 3 < T) {
                P0 = *reinterpret_cast<const float4*>(xrow + (size_t)(cNext * 4 + 0) * NH);
                P1 = *reinterpret_cast<const float4*>(xrow + (size_t)(cNext * 4 + 1) * NH);
                P2 = *reinterpret_cast<const float4*>(xrow + (size_t)(cNext * 4 + 2) * NH);
                P3 = *reinterpret_cast<const float4*>(xrow + (size_t)(cNext * 4 + 3) * NH);
            }
        }
        __syncthreads();   // list reads done; wcnt + staged xin visible

        // ---- phase 2: cross-wave exclusive prefix (2 x int4 LDS reads)
        const int4 c0 = *reinterpret_cast<const int4*>(&wcnt[hb][0]);
        const int4 c1 = *reinterpret_cast<const int4*>(&wcnt[hb][4]);
        int pre = 0;
        pre += (wv > 0) ? c0.x : 0;
        pre += (wv > 1) ? c0.y : 0;
        pre += (wv > 2) ? c0.z : 0;
        pre += (wv > 3) ? c0.w : 0;
        pre += (wv > 4) ? c1.x : 0;
        pre += (wv > 5) ? c1.y : 0;
        pre += (wv > 6) ? c1.z : 0;
        const int tot = ((c0.x + c0.y) + (c0.z + c0.w)) + ((c1.x + c1.y) + (c1.z + c1.w));

        const int gaLo = (int)__popcll(ba & lo32);
        const int gbLo = (int)__popcll(bb & lo32);
        const int gcLo = (int)__popcll(bc & lo32);
        const int gdLo = (int)__popcll(bd & lo32);
        const int g0 = gaLo + gcLo;                                   // comps{0,2} lanes<32
        const int g1 = gbLo + gdLo;                                   // comps{1,3} lanes<32
        const int g2 = (int)(__popcll(ba) + __popcll(bc)) - g0;       // comps{0,2} lanes>=32
        const int base02 = (lane < 32) ? 0 : (g0 + g1);
        const int base13 = (lane < 32) ? g0 : ((g0 + g1) + g2);
        const int pa = (int)__popcll(ba & mb);
        const int pb = (int)__popcll(bb & mb);
        const int pc = (int)__popcll(bc & mb);
        const int pd = (int)__popcll(bd & mb);
        const int o02 = pre + base02 + pa + pc;
        const int o13 = pre + base13 + pb + pd;
        if (s[0] > 0.0f) list[hb][o02] = n0;
        if (s[2] > 0.0f) list[hb][o02 + (int)((ba >> lane) & 1ull)] = n0 + 2;
        if (s[1] > 0.0f) list[hb][o13] = n0 + 1;
        if (s[3] > 0.0f) list[hb][o13 + (int)((bb >> lane) & 1ull)] = n0 + 3;
        nact = tot;
        if (!USE_XIN) {
            if (t + 1 < T && tl < NI) xt[hb][tl] = x[((size_t)b * T + (t + 1)) * NI + tl];
        }
        __syncthreads();   // list visible for next step
    }
#undef ISSUE
#undef ACC

    float4 o;
    o.x = cnt[0] / (float)T;
    o.y = cnt[1] / (float)T;
    o.z = cnt[2] / (float)T;
    o.w = cnt[3] / (float)T;
    *reinterpret_cast<float4*>(out + (size_t)b * NH + n0) = o;
}

// ---- wrappers with LITERAL resource attributes (no template-dependent args) ----
template <int USE_XIN>
__global__ __launch_bounds__(512) void esn_seq1(
    const float* __restrict__ xin, const float* __restrict__ x,
    const float* __restrict__ x2h, const float* __restrict__ h2h,
    const float* __restrict__ bias, float* __restrict__ out, int T)
{
    esn_body<USE_XIN, 1>(xin, x, x2h, h2h, bias, out, T);
}

template <int USE_XIN>
__global__
__attribute__((amdgpu_flat_work_group_size(1024, 1024)))
__attribute__((amdgpu_waves_per_eu(4, 4)))   // pin 4 waves/EU -> VGPR budget 128
void esn_seq2(
    const float* __restrict__ xin, const float* __restrict__ x,
    const float* __restrict__ x2h, const float* __restrict__ h2h,
    const float* __restrict__ bias, float* __restrict__ out, int T)
{
    esn_body<USE_XIN, 2>(xin, x, x2h, h2h, bias, out, T);
}

extern "C" void kernel_launch(void* const* d_in, const int* in_sizes, int n_in,
                              void* d_out, int out_size, void* d_ws, size_t ws_size,
                              hipStream_t stream) {
    const float* x    = (const float*)d_in[0];   // [B,T,96]
    const float* x2h  = (const float*)d_in[1];   // [96,2048]
    const float* h2h  = (const float*)d_in[2];   // [2048,2048]
    const float* bias = (const float*)d_in[3];   // [2048]
    float* out = (float*)d_out;

    const int M = in_sizes[0] / NI;   // B*T
    const int T = 1024;
    const int B = M / T;

    const size_t xin_bytes = (size_t)M * NH * sizeof(float);
    if (ws_size >= xin_bytes) {
        float* xin = (float*)d_ws;
        dim3 grid(NH / 64, M / 64);
        xin_gemm<<<grid, 256, 0, stream>>>(x, x2h, xin);
        if ((B & 1) == 0 && B >= 2) {
            esn_seq2<1><<<B / 2, 1024, 0, stream>>>(xin, x, x2h, h2h, bias, out, T);
        } else {
            esn_seq1<1><<<B, 512, 0, stream>>>(xin, x, x2h, h2h, bias, out, T);
        }
    } else {
        if ((B & 1) == 0 && B >= 2) {
            esn_seq2<0><<<B / 2, 1024, 0, stream>>>(x /*unused*/, x, x2h, h2h, bias, out, T);
        } else {
            esn_seq1<0><<<B, 512, 0, stream>>>(x /*unused*/, x, x2h, h2h, bias, out, T);
        }
    }
}

// Round 8
// 1800.566 us; speedup vs baseline: 6.3879x; 6.3442x over previous
//
#include <hip/hip_runtime.h>
#include <cmath>

#define NH 2048
#define NI 96

// ---------------- GEMM: xin[b,t,:] = x[b,t,:] @ x2h ----------------
__global__ __launch_bounds__(256) void xin_gemm(
    const float* __restrict__ A,
    const float* __restrict__ Bm,
    float* __restrict__ C)
{
    __shared__ float At[96][68];
    __shared__ float Bt[96][68];
    const int tid = threadIdx.x;
    const int rowBase = blockIdx.y * 64;
    const int colBase = blockIdx.x * 64;

    {
        const int r = tid >> 2;
        const int sub = tid & 3;
        const float4* Arow = reinterpret_cast<const float4*>(A + (size_t)(rowBase + r) * NI);
        #pragma unroll
        for (int q = 0; q < 6; ++q) {
            const int k4 = sub + 4 * q;
            float4 v = Arow[k4];
            At[k4 * 4 + 0][r] = v.x;
            At[k4 * 4 + 1][r] = v.y;
            At[k4 * 4 + 2][r] = v.z;
            At[k4 * 4 + 3][r] = v.w;
        }
    }
    {
        const int c4 = tid & 15;
        const int k0 = tid >> 4;
        #pragma unroll
        for (int g = 0; g < 6; ++g) {
            const int kk = k0 + 16 * g;
            float4 v = *reinterpret_cast<const float4*>(Bm + (size_t)kk * NH + colBase + c4 * 4);
            *reinterpret_cast<float4*>(&Bt[kk][c4 * 4]) = v;
        }
    }
    __syncthreads();

    const int ty = tid >> 4, tx = tid & 15;
    float acc[4][4] = {};
    #pragma unroll 8
    for (int kk = 0; kk < 96; ++kk) {
        float4 a = *reinterpret_cast<const float4*>(&At[kk][ty * 4]);
        float4 b = *reinterpret_cast<const float4*>(&Bt[kk][tx * 4]);
        acc[0][0] += a.x * b.x; acc[0][1] += a.x * b.y; acc[0][2] += a.x * b.z; acc[0][3] += a.x * b.w;
        acc[1][0] += a.y * b.x; acc[1][1] += a.y * b.y; acc[1][2] += a.y * b.z; acc[1][3] += a.y * b.w;
        acc[2][0] += a.z * b.x; acc[2][1] += a.z * b.y; acc[2][2] += a.z * b.z; acc[2][3] += a.z * b.w;
        acc[3][0] += a.w * b.x; acc[3][1] += a.w * b.y; acc[3][2] += a.w * b.z; acc[3][3] += a.w * b.w;
    }
    #pragma unroll
    for (int i = 0; i < 4; ++i) {
        float4 o;
        o.x = acc[i][0]; o.y = acc[i][1]; o.z = acc[i][2]; o.w = acc[i][3];
        *reinterpret_cast<float4*>(C + (size_t)(rowBase + ty * 4 + i) * NH + colBase + tx * 4) = o;
    }
}

// ---------------- Dual-batch sequential recurrence ----------------
// 512 threads; thread owns neurons n0..n0+3 of batch 2i (A) AND batch 2i+1 (B).
// R5-R7 lesson: 1024-thread workgroups are pinned to 64 VGPR by the backend
// (3 attribute spellings all ignored -> full pipeline spill, 10x regression).
// 512-thread + __launch_bounds__(512,2) is PROVEN to honor ~116+ VGPR (R4).
// Co-location of the two recurrences is done per-thread: the gather runs a
// merged task list (task = 4-row group of A or B, interleaved A,B,A,B...,
// then the longer batch's remainder) through one 4-stage rotated pipeline,
// so both batches' LLC latency heads overlap and every VALU phase has two
// independent dep chains. Per batch, group order/accumulator mapping/tail
// handling/compaction are IDENTICAL to R4 -> bit-exact (absmax 0.0).
// bias rows are the same for A and B (same n0) -> shared bs regs.
template <int USE_XIN>
__global__ __launch_bounds__(512, 2) void esn_dual(
    const float* __restrict__ xin,   // [B*T*NH]
    const float* __restrict__ x,     // [B*T*NI] fallback
    const float* __restrict__ x2h,   // [NI*NH]
    const float* __restrict__ h2h,   // [NH*NH]
    const float* __restrict__ bias,  // [NH]
    float* __restrict__ out,         // [B*NH]
    int T)
{
    const int tid = threadIdx.x;
    const int n0 = tid * 4;
    const int wv = tid >> 6;
    const int lane = tid & 63;
    const int b0 = blockIdx.x * 2;

    __shared__ alignas(16) int list[2][NH];
    __shared__ alignas(16) int wcnt[2][8];
    __shared__ float xt[2][NI];
    __shared__ alignas(16) float xstage[2][2][2][NH];  // [batch][buf][step-in-chunk2][NH]

    constexpr float DT = 0.075f;
    constexpr float TAU_M = 0.5f;
    constexpr float GGAMMA = 2.7f;
    constexpr float GEPS = 4.7f;
    constexpr float GAIN = 5.0f;
    const float ref_decay = expf(-0.075f / 0.25f);

    float lvA[4] = {0,0,0,0}, hyA[4] = {0,0,0,0}, hzA[4] = {0,0,0,0};
    float rfA[4] = {0,0,0,0}, cntA[4] = {0,0,0,0};
    float lvB[4] = {0,0,0,0}, hyB[4] = {0,0,0,0}, hzB[4] = {0,0,0,0};
    float rfB[4] = {0,0,0,0}, cntB[4] = {0,0,0,0};
    float bs[4];
    {
        const float4 b4 = *reinterpret_cast<const float4*>(&bias[n0]);
        bs[0] = b4.x; bs[1] = b4.y; bs[2] = b4.z; bs[3] = b4.w;
    }
    int nactA = 0, nactB = 0;

    const float* __restrict__ xrowA = USE_XIN ? (xin + (size_t)b0 * T * NH + n0) : xin;
    const float* __restrict__ xrowB = USE_XIN ? (xin + (size_t)(b0 + 1) * T * NH + n0) : xin;

    // next-chunk (2 steps) xin staging registers per batch
    float4 PA0, PA1, PB0, PB1;

    if (USE_XIN) {
        *reinterpret_cast<float4*>(&xstage[0][0][0][n0]) = *reinterpret_cast<const float4*>(xrowA + 0 * NH);
        *reinterpret_cast<float4*>(&xstage[0][0][1][n0]) = *reinterpret_cast<const float4*>(xrowA + 1 * NH);
        *reinterpret_cast<float4*>(&xstage[1][0][0][n0]) = *reinterpret_cast<const float4*>(xrowB + 0 * NH);
        *reinterpret_cast<float4*>(&xstage[1][0][1][n0]) = *reinterpret_cast<const float4*>(xrowB + 1 * NH);
        PA0 = *reinterpret_cast<const float4*>(xrowA + 2 * NH);
        PA1 = *reinterpret_cast<const float4*>(xrowA + 3 * NH);
        PB0 = *reinterpret_cast<const float4*>(xrowB + 2 * NH);
        PB1 = *reinterpret_cast<const float4*>(xrowB + 3 * NH);
    } else {
        if (tid < NI) {
            xt[0][tid] = x[(size_t)b0 * T * NI + tid];
            xt[1][tid] = x[(size_t)(b0 + 1) * T * NI + tid];
        }
    }
    __syncthreads();

    const unsigned long long below = (1ull << lane) - 1ull;
    const unsigned long long lo32 = 0xFFFFFFFFull;
    const unsigned long long mb = (lane >= 32) ? (below & ~lo32) : below;

    const int4* __restrict__ L4A = reinterpret_cast<const int4*>(&list[0][0]);
    const int4* __restrict__ L4B = reinterpret_cast<const int4*>(&list[1][0]);

// merged-task pipeline: task i -> (batch bt_, group gr_). Interleaved region
// (i < m2): even i = A group i/2, odd i = B group i/2; remainder: the longer
// batch's groups mG.. ascending. Stage = i%4; BT<St> records the stage's batch.
#define ISSUE2(St, i) do {                                                               \
        const int bt_ = ((i) < m2) ? ((i) & 1) : extraBt;                                \
        const int gr_ = ((i) < m2) ? ((i) >> 1) : (mG + (i) - m2);                       \
        BT##St = bt_;                                                                    \
        I##St = bt_ ? L4B[gr_] : L4A[gr_];                                               \
        const float* pr0 = h2h + (size_t)__builtin_amdgcn_readfirstlane(I##St.x) * NH;   \
        const float* pr1 = h2h + (size_t)__builtin_amdgcn_readfirstlane(I##St.y) * NH;   \
        const float* pr2 = h2h + (size_t)__builtin_amdgcn_readfirstlane(I##St.z) * NH;   \
        const float* pr3 = h2h + (size_t)__builtin_amdgcn_readfirstlane(I##St.w) * NH;   \
        W##St##_0 = *reinterpret_cast<const float4*>(pr0 + n0);                          \
        W##St##_1 = *reinterpret_cast<const float4*>(pr1 + n0);                          \
        W##St##_2 = *reinterpret_cast<const float4*>(pr2 + n0);                          \
        W##St##_3 = *reinterpret_cast<const float4*>(pr3 + n0);                          \
    } while (0)
#define ACC2(St) do {                                                                    \
        if (BT##St == 0) {                                                               \
            aA0[0] += W##St##_0.x; aA0[1] += W##St##_0.y; aA0[2] += W##St##_0.z; aA0[3] += W##St##_0.w; \
            aA1[0] += W##St##_1.x; aA1[1] += W##St##_1.y; aA1[2] += W##St##_1.z; aA1[3] += W##St##_1.w; \
            aA2[0] += W##St##_2.x; aA2[1] += W##St##_2.y; aA2[2] += W##St##_2.z; aA2[3] += W##St##_2.w; \
            aA3[0] += W##St##_3.x; aA3[1] += W##St##_3.y; aA3[2] += W##St##_3.z; aA3[3] += W##St##_3.w; \
        } else {                                                                         \
            aB0[0] += W##St##_0.x; aB0[1] += W##St##_0.y; aB0[2] += W##St##_0.z; aB0[3] += W##St##_0.w; \
            aB1[0] += W##St##_1.x; aB1[1] += W##St##_1.y; aB1[2] += W##St##_1.z; aB1[3] += W##St##_1.w; \
            aB2[0] += W##St##_2.x; aB2[1] += W##St##_2.y; aB2[2] += W##St##_2.z; aB2[3] += W##St##_2.w; \
            aB3[0] += W##St##_3.x; aB3[1] += W##St##_3.y; aB3[2] += W##St##_3.z; aB3[3] += W##St##_3.w; \
        }                                                                                \
    } while (0)

    for (int t = 0; t < T; ++t) {
        float4 xiA, xiB;
        if (USE_XIN) {
            xiA = *reinterpret_cast<const float4*>(&xstage[0][(t >> 1) & 1][t & 1][n0]);
            xiB = *reinterpret_cast<const float4*>(&xstage[1][(t >> 1) & 1][t & 1][n0]);
        }

        float aA0[4] = {0,0,0,0}, aA1[4] = {0,0,0,0}, aA2[4] = {0,0,0,0}, aA3[4] = {0,0,0,0};
        float aB0[4] = {0,0,0,0}, aB1[4] = {0,0,0,0}, aB2[4] = {0,0,0,0}, aB3[4] = {0,0,0,0};

        const int n4A = nactA & ~3, GA = n4A >> 2, tcA = nactA - n4A;
        const int n4B = nactB & ~3, GB = n4B >> 2, tcB = nactB - n4B;
        const int mG = (GA < GB) ? GA : GB;
        const int m2 = 2 * mG;
        const int NT = GA + GB;
        const int extraBt = (GA > GB) ? 0 : 1;

        int4 I0, I1, I2, I3;
        int BT0, BT1, BT2, BT3;
        float4 W0_0, W0_1, W0_2, W0_3;
        float4 W1_0, W1_1, W1_2, W1_3;
        float4 W2_0, W2_1, W2_2, W2_3;
        float4 W3_0, W3_1, W3_2, W3_3;

        // prologue: fill 4 stages + both tails (all issued before any wait)
        if (0 < NT) ISSUE2(0, 0);
        if (1 < NT) ISSUE2(1, 1);
        if (2 < NT) ISSUE2(2, 2);
        if (3 < NT) ISSUE2(3, 3);
        float4 twA0, twA1, twA2, twB0, twB1, twB2;
        if (tcA > 0) {
            const float* p = h2h + (size_t)__builtin_amdgcn_readfirstlane(list[0][n4A]) * NH;
            twA0 = *reinterpret_cast<const float4*>(p + n0);
        }
        if (tcA > 1) {
            const float* p = h2h + (size_t)__builtin_amdgcn_readfirstlane(list[0][n4A + 1]) * NH;
            twA1 = *reinterpret_cast<const float4*>(p + n0);
        }
        if (tcA > 2) {
            const float* p = h2h + (size_t)__builtin_amdgcn_readfirstlane(list[0][n4A + 2]) * NH;
            twA2 = *reinterpret_cast<const float4*>(p + n0);
        }
        if (tcB > 0) {
            const float* p = h2h + (size_t)__builtin_amdgcn_readfirstlane(list[1][n4B]) * NH;
            twB0 = *reinterpret_cast<const float4*>(p + n0);
        }
        if (tcB > 1) {
            const float* p = h2h + (size_t)__builtin_amdgcn_readfirstlane(list[1][n4B + 1]) * NH;
            twB1 = *reinterpret_cast<const float4*>(p + n0);
        }
        if (tcB > 2) {
            const float* p = h2h + (size_t)__builtin_amdgcn_readfirstlane(list[1][n4B + 2]) * NH;
            twB2 = *reinterpret_cast<const float4*>(p + n0);
        }

        // steady state over merged tasks
        int tk = 0;
        for (; tk + 4 <= NT; tk += 4) {
            ACC2(0); if (tk + 4 < NT) ISSUE2(0, tk + 4);
            ACC2(1); if (tk + 5 < NT) ISSUE2(1, tk + 5);
            ACC2(2); if (tk + 6 < NT) ISSUE2(2, tk + 6);
            ACC2(3); if (tk + 7 < NT) ISSUE2(3, tk + 7);
        }
        if (tk + 0 < NT) ACC2(0);
        if (tk + 1 < NT) ACC2(1);
        if (tk + 2 < NT) ACC2(2);
        // tails fold into a0 in list order (bit-exact per batch, after all groups)
        if (tcA > 0) { aA0[0] += twA0.x; aA0[1] += twA0.y; aA0[2] += twA0.z; aA0[3] += twA0.w; }
        if (tcA > 1) { aA0[0] += twA1.x; aA0[1] += twA1.y; aA0[2] += twA1.z; aA0[3] += twA1.w; }
        if (tcA > 2) { aA0[0] += twA2.x; aA0[1] += twA2.y; aA0[2] += twA2.z; aA0[3] += twA2.w; }
        if (tcB > 0) { aB0[0] += twB0.x; aB0[1] += twB0.y; aB0[2] += twB0.z; aB0[3] += twB0.w; }
        if (tcB > 1) { aB0[0] += twB1.x; aB0[1] += twB1.y; aB0[2] += twB1.z; aB0[3] += twB1.w; }
        if (tcB > 2) { aB0[0] += twB2.x; aB0[1] += twB2.y; aB0[2] += twB2.z; aB0[3] += twB2.w; }

        float icA[4], icB[4];
        if (USE_XIN) {
            const float xivA[4] = {xiA.x, xiA.y, xiA.z, xiA.w};
            const float xivB[4] = {xiB.x, xiB.y, xiB.z, xiB.w};
            #pragma unroll
            for (int c = 0; c < 4; ++c) {
                const float recA = (aA0[c] + aA1[c]) + (aA2[c] + aA3[c]);
                icA[c] = (xivA[c] + recA) + bs[c];
                const float recB = (aB0[c] + aB1[c]) + (aB2[c] + aB3[c]);
                icB[c] = (xivB[c] + recB) + bs[c];
            }
        } else {
            float mA[4] = {0,0,0,0}, mB[4] = {0,0,0,0};
            for (int i = 0; i < NI; ++i) {
                const float xvA = xt[0][i];
                const float xvB = xt[1][i];
                const float4 w = *reinterpret_cast<const float4*>(&x2h[(size_t)i * NH + n0]);
                mA[0] += xvA * w.x; mA[1] += xvA * w.y; mA[2] += xvA * w.z; mA[3] += xvA * w.w;
                mB[0] += xvB * w.x; mB[1] += xvB * w.y; mB[2] += xvB * w.z; mB[3] += xvB * w.w;
            }
            #pragma unroll
            for (int c = 0; c < 4; ++c) {
                const float recA = (aA0[c] + aA1[c]) + (aA2[c] + aA3[c]);
                icA[c] = (mA[c] + recA) + bs[c];
                const float recB = (aB0[c] + aB1[c]) + (aB2[c] + aB3[c]);
                icB[c] = (mB[c] + recB) + bs[c];
            }
        }

        // ---- LIF + RF oscillator, both batches (same expressions as R4)
        float sA[4], sB[4];
        #pragma unroll
        for (int c = 0; c < 4; ++c) {
            lvA[c] = lvA[c] + DT * (-lvA[c] / TAU_M + icA[c]);
            const float lsA = lvA[c] > 1.0f ? 1.0f : 0.0f;
            lvA[c] -= lsA;
            hzA[c] = hzA[c] + DT * ((GAIN * lsA - GGAMMA * hyA[c]) - GEPS * hzA[c]);
            hyA[c] = hyA[c] + DT * hzA[c];
            sA[c] = ((hyA[c] - 1.0f) - rfA[c]) > 0.0f ? 1.0f : 0.0f;
            rfA[c] = rfA[c] * ref_decay + sA[c];
            cntA[c] += sA[c];

            lvB[c] = lvB[c] + DT * (-lvB[c] / TAU_M + icB[c]);
            const float lsB = lvB[c] > 1.0f ? 1.0f : 0.0f;
            lvB[c] -= lsB;
            hzB[c] = hzB[c] + DT * ((GAIN * lsB - GGAMMA * hyB[c]) - GEPS * hzB[c]);
            hyB[c] = hyB[c] + DT * hzB[c];
            sB[c] = ((hyB[c] - 1.0f) - rfB[c]) > 0.0f ? 1.0f : 0.0f;
            rfB[c] = rfB[c] * ref_decay + sB[c];
            cntB[c] += sB[c];
        }

        // ---- ballots, both batches (deterministic order per batch = R4's)
        const unsigned long long baA = __ballot(sA[0] > 0.0f);
        const unsigned long long bbA = __ballot(sA[1] > 0.0f);
        const unsigned long long bcA = __ballot(sA[2] > 0.0f);
        const unsigned long long bdA = __ballot(sA[3] > 0.0f);
        const unsigned long long baB = __ballot(sB[0] > 0.0f);
        const unsigned long long bbB = __ballot(sB[1] > 0.0f);
        const unsigned long long bcB = __ballot(sB[2] > 0.0f);
        const unsigned long long bdB = __ballot(sB[3] > 0.0f);
        if (lane == 0) {
            wcnt[0][wv] = (int)(__popcll(baA) + __popcll(bbA) + __popcll(bcA) + __popcll(bdA));
            wcnt[1][wv] = (int)(__popcll(baB) + __popcll(bbB) + __popcll(bcB) + __popcll(bdB));
        }

        // ---- chunk boundary (every 2 steps): commit P (loaded 2 steps ago),
        // issue chunk c+2. xstage slots are thread-private -> race-free.
        if (USE_XIN && ((t & 1) == 1)) {
            const int bufW = ((t >> 1) + 1) & 1;
            *reinterpret_cast<float4*>(&xstage[0][bufW][0][n0]) = PA0;
            *reinterpret_cast<float4*>(&xstage[0][bufW][1][n0]) = PA1;
            *reinterpret_cast<float4*>(&xstage[1][bufW][0][n0]) = PB0;
            *reinterpret_cast<float4*>(&xstage[1][bufW][1][n0]) = PB1;
            const int cN = (t >> 1) + 2;
            if (cN * 2 + 1 < T) {
                PA0 = *reinterpret_cast<const float4*>(xrowA + (size_t)(cN * 2 + 0) * NH);
                PA1 = *reinterpret_cast<const float4*>(xrowA + (size_t)(cN * 2 + 1) * NH);
                PB0 = *reinterpret_cast<const float4*>(xrowB + (size_t)(cN * 2 + 0) * NH);
                PB1 = *reinterpret_cast<const float4*>(xrowB + (size_t)(cN * 2 + 1) * NH);
            }
        }
        __syncthreads();   // list reads done; wcnt visible

        // ---- phase 2: per-batch cross-wave prefix + compacted list write
        {
            const int4 c0 = *reinterpret_cast<const int4*>(&wcnt[0][0]);
            const int4 c1 = *reinterpret_cast<const int4*>(&wcnt[0][4]);
            int pre = 0;
            pre += (wv > 0) ? c0.x : 0;
            pre += (wv > 1) ? c0.y : 0;
            pre += (wv > 2) ? c0.z : 0;
            pre += (wv > 3) ? c0.w : 0;
            pre += (wv > 4) ? c1.x : 0;
            pre += (wv > 5) ? c1.y : 0;
            pre += (wv > 6) ? c1.z : 0;
            nactA = ((c0.x + c0.y) + (c0.z + c0.w)) + ((c1.x + c1.y) + (c1.z + c1.w));

            const int gaLo = (int)__popcll(baA & lo32);
            const int gbLo = (int)__popcll(bbA & lo32);
            const int gcLo = (int)__popcll(bcA & lo32);
            const int gdLo = (int)__popcll(bdA & lo32);
            const int g0 = gaLo + gcLo;
            const int g1 = gbLo + gdLo;
            const int g2 = (int)(__popcll(baA) + __popcll(bcA)) - g0;
            const int base02 = (lane < 32) ? 0 : (g0 + g1);
            const int base13 = (lane < 32) ? g0 : ((g0 + g1) + g2);
            const int pa = (int)__popcll(baA & mb);
            const int pb = (int)__popcll(bbA & mb);
            const int pc = (int)__popcll(bcA & mb);
            const int pd = (int)__popcll(bdA & mb);
            const int o02 = pre + base02 + pa + pc;
            const int o13 = pre + base13 + pb + pd;
            if (sA[0] > 0.0f) list[0][o02] = n0;
            if (sA[2] > 0.0f) list[0][o02 + (int)((baA >> lane) & 1ull)] = n0 + 2;
            if (sA[1] > 0.0f) list[0][o13] = n0 + 1;
            if (sA[3] > 0.0f) list[0][o13 + (int)((bbA >> lane) & 1ull)] = n0 + 3;
        }
        {
            const int4 c0 = *reinterpret_cast<const int4*>(&wcnt[1][0]);
            const int4 c1 = *reinterpret_cast<const int4*>(&wcnt[1][4]);
            int pre = 0;
            pre += (wv > 0) ? c0.x : 0;
            pre += (wv > 1) ? c0.y : 0;
            pre += (wv > 2) ? c0.z : 0;
            pre += (wv > 3) ? c0.w : 0;
            pre += (wv > 4) ? c1.x : 0;
            pre += (wv > 5) ? c1.y : 0;
            pre += (wv > 6) ? c1.z : 0;
            nactB = ((c0.x + c0.y) + (c0.z + c0.w)) + ((c1.x + c1.y) + (c1.z + c1.w));

            const int gaLo = (int)__popcll(baB & lo32);
            const int gbLo = (int)__popcll(bbB & lo32);
            const int gcLo = (int)__popcll(bcB & lo32);
            const int gdLo = (int)__popcll(bdB & lo32);
            const int g0 = gaLo + gcLo;
            const int g1 = gbLo + gdLo;
            const int g2 = (int)(__popcll(baB) + __popcll(bcB)) - g0;
            const int base02 = (lane < 32) ? 0 : (g0 + g1);
            const int base13 = (lane < 32) ? g0 : ((g0 + g1) + g2);
            const int pa = (int)__popcll(baB & mb);
            const int pb = (int)__popcll(bbB & mb);
            const int pc = (int)__popcll(bcB & mb);
            const int pd = (int)__popcll(bdB & mb);
            const int o02 = pre + base02 + pa + pc;
            const int o13 = pre + base13 + pb + pd;
            if (sB[0] > 0.0f) list[1][o02] = n0;
            if (sB[2] > 0.0f) list[1][o02 + (int)((baB >> lane) & 1ull)] = n0 + 2;
            if (sB[1] > 0.0f) list[1][o13] = n0 + 1;
            if (sB[3] > 0.0f) list[1][o13 + (int)((bbB >> lane) & 1ull)] = n0 + 3;
        }
        if (!USE_XIN) {
            if (t + 1 < T && tid < NI) {
                xt[0][tid] = x[((size_t)b0 * T + (t + 1)) * NI + tid];
                xt[1][tid] = x[((size_t)(b0 + 1) * T + (t + 1)) * NI + tid];
            }
        }
        __syncthreads();   // lists visible for next step
    }
#undef ISSUE2
#undef ACC2

    float4 oA, oB;
    oA.x = cntA[0] / (float)T; oA.y = cntA[1] / (float)T;
    oA.z = cntA[2] / (float)T; oA.w = cntA[3] / (float)T;
    oB.x = cntB[0] / (float)T; oB.y = cntB[1] / (float)T;
    oB.z = cntB[2] / (float)T; oB.w = cntB[3] / (float)T;
    *reinterpret_cast<float4*>(out + (size_t)b0 * NH + n0) = oA;
    *reinterpret_cast<float4*>(out + (size_t)(b0 + 1) * NH + n0) = oB;
}

// ---------------- Single-batch fallback (R4 verbatim; odd B only) ----------------
template <int USE_XIN>
__global__ __launch_bounds__(512) void esn_seq1(
    const float* __restrict__ xin,
    const float* __restrict__ x,
    const float* __restrict__ x2h,
    const float* __restrict__ h2h,
    const float* __restrict__ bias,
    float* __restrict__ out,
    int T)
{
    const int b = blockIdx.x;
    const int tid = threadIdx.x;
    const int n0 = tid * 4;
    const int wv = tid >> 6;
    const int lane = tid & 63;

    __shared__ alignas(16) int list[NH];
    __shared__ alignas(16) int wcnt[8];
    __shared__ float xt[NI];
    __shared__ alignas(16) float xstage[2][4][NH];

    constexpr float DT = 0.075f;
    constexpr float TAU_M = 0.5f;
    constexpr float GGAMMA = 2.7f;
    constexpr float GEPS = 4.7f;
    constexpr float GAIN = 5.0f;
    const float ref_decay = expf(-0.075f / 0.25f);

    float lv[4] = {0,0,0,0}, hy[4] = {0,0,0,0}, hz[4] = {0,0,0,0};
    float rf[4] = {0,0,0,0}, cnt[4] = {0,0,0,0};
    float bs[4];
    {
        const float4 b4 = *reinterpret_cast<const float4*>(&bias[n0]);
        bs[0] = b4.x; bs[1] = b4.y; bs[2] = b4.z; bs[3] = b4.w;
    }
    int nact = 0;

    const float* __restrict__ xrow = USE_XIN ? (xin + (size_t)b * T * NH + n0) : xin;
    float4 P0, P1, P2, P3;

    if (USE_XIN) {
        #pragma unroll
        for (int r = 0; r < 4; ++r) {
            float4 v = *reinterpret_cast<const float4*>(xrow + (size_t)r * NH);
            *reinterpret_cast<float4*>(&xstage[0][r][n0]) = v;
        }
        P0 = *reinterpret_cast<const float4*>(xrow + (size_t)4 * NH);
        P1 = *reinterpret_cast<const float4*>(xrow + (size_t)5 * NH);
        P2 = *reinterpret_cast<const float4*>(xrow + (size_t)6 * NH);
        P3 = *reinterpret_cast<const float4*>(xrow + (size_t)7 * NH);
    } else {
        if (tid < NI) xt[tid] = x[(size_t)b * T * NI + tid];
    }
    __syncthreads();

    const unsigned long long below = (1ull << lane) - 1ull;
    const unsigned long long lo32 = 0xFFFFFFFFull;
    const unsigned long long mb = (lane >= 32) ? (below & ~lo32) : below;
    const int4* __restrict__ L4 = reinterpret_cast<const int4*>(list);

#define ISSUE1(St, grp) do {                                                             \
        I##St = L4[(grp)];                                                               \
        const float* pr0 = h2h + (size_t)__builtin_amdgcn_readfirstlane(I##St.x) * NH;   \
        const float* pr1 = h2h + (size_t)__builtin_amdgcn_readfirstlane(I##St.y) * NH;   \
        const float* pr2 = h2h + (size_t)__builtin_amdgcn_readfirstlane(I##St.z) * NH;   \
        const float* pr3 = h2h + (size_t)__builtin_amdgcn_readfirstlane(I##St.w) * NH;   \
        W##St##_0 = *reinterpret_cast<const float4*>(pr0 + n0);                          \
        W##St##_1 = *reinterpret_cast<const float4*>(pr1 + n0);                          \
        W##St##_2 = *reinterpret_cast<const float4*>(pr2 + n0);                          \
        W##St##_3 = *reinterpret_cast<const float4*>(pr3 + n0);                          \
    } while (0)
#define ACC1(St) do {                                                                    \
        a0[0] += W##St##_0.x; a0[1] += W##St##_0.y; a0[2] += W##St##_0.z; a0[3] += W##St##_0.w; \
        a1[0] += W##St##_1.x; a1[1] += W##St##_1.y; a1[2] += W##St##_1.z; a1[3] += W##St##_1.w; \
        a2[0] += W##St##_2.x; a2[1] += W##St##_2.y; a2[2] += W##St##_2.z; a2[3] += W##St##_2.w; \
        a3[0] += W##St##_3.x; a3[1] += W##St##_3.y; a3[2] += W##St##_3.z; a3[3] += W##St##_3.w; \
    } while (0)

    for (int t = 0; t < T; ++t) {
        float4 xi;
        if (USE_XIN) xi = *reinterpret_cast<const float4*>(&xstage[(t >> 2) & 1][t & 3][n0]);

        float a0[4] = {0,0,0,0}, a1[4] = {0,0,0,0}, a2[4] = {0,0,0,0}, a3[4] = {0,0,0,0};
        const int n4 = nact & ~3;
        const int G = n4 >> 2;
        const int tc = nact - n4;

        int4 I0, I1, I2, I3;
        float4 W0_0, W0_1, W0_2, W0_3;
        float4 W1_0, W1_1, W1_2, W1_3;
        float4 W2_0, W2_1, W2_2, W2_3;
        float4 W3_0, W3_1, W3_2, W3_3;

        if (0 < G) ISSUE1(0, 0);
        if (1 < G) ISSUE1(1, 1);
        if (2 < G) ISSUE1(2, 2);
        if (3 < G) ISSUE1(3, 3);
        float4 tw0, tw1, tw2;
        if (tc > 0) {
            const float* p = h2h + (size_t)__builtin_amdgcn_readfirstlane(list[n4]) * NH;
            tw0 = *reinterpret_cast<const float4*>(p + n0);
        }
        if (tc > 1) {
            const float* p = h2h + (size_t)__builtin_amdgcn_readfirstlane(list[n4 + 1]) * NH;
            tw1 = *reinterpret_cast<const float4*>(p + n0);
        }
        if (tc > 2) {
            const float* p = h2h + (size_t)__builtin_amdgcn_readfirstlane(list[n4 + 2]) * NH;
            tw2 = *reinterpret_cast<const float4*>(p + n0);
        }

        int g = 0;
        for (; g + 4 <= G; g += 4) {
            const bool r0 = (g + 4 < G), r1 = (g + 5 < G), r2 = (g + 6 < G), r3 = (g + 7 < G);
            ACC1(0); if (r0) ISSUE1(0, g + 4);
            ACC1(1); if (r1) ISSUE1(1, g + 5);
            ACC1(2); if (r2) ISSUE1(2, g + 6);
            ACC1(3); if (r3) ISSUE1(3, g + 7);
        }
        if (g + 0 < G) ACC1(0);
        if (g + 1 < G) ACC1(1);
        if (g + 2 < G) ACC1(2);
        if (tc > 0) { a0[0] += tw0.x; a0[1] += tw0.y; a0[2] += tw0.z; a0[3] += tw0.w; }
        if (tc > 1) { a0[0] += tw1.x; a0[1] += tw1.y; a0[2] += tw1.z; a0[3] += tw1.w; }
        if (tc > 2) { a0[0] += tw2.x; a0[1] += tw2.y; a0[2] += tw2.z; a0[3] += tw2.w; }

        float ic[4];
        if (USE_XIN) {
            const float xiv[4] = {xi.x, xi.y, xi.z, xi.w};
            #pragma unroll
            for (int c = 0; c < 4; ++c) {
                const float rec = (a0[c] + a1[c]) + (a2[c] + a3[c]);
                ic[c] = (xiv[c] + rec) + bs[c];
            }
        } else {
            float m[4] = {0,0,0,0};
            for (int i = 0; i < NI; ++i) {
                const float xv = xt[i];
                const float4 w = *reinterpret_cast<const float4*>(&x2h[(size_t)i * NH + n0]);
                m[0] += xv * w.x; m[1] += xv * w.y; m[2] += xv * w.z; m[3] += xv * w.w;
            }
            #pragma unroll
            for (int c = 0; c < 4; ++c) {
                const float rec = (a0[c] + a1[c]) + (a2[c] + a3[c]);
                ic[c] = (m[c] + rec) + bs[c];
            }
        }

        float s[4];
        #pragma unroll
        for (int c = 0; c < 4; ++c) {
            lv[c] = lv[c] + DT * (-lv[c] / TAU_M + ic[c]);
            const float ls = lv[c] > 1.0f ? 1.0f : 0.0f;
            lv[c] -= ls;
            hz[c] = hz[c] + DT * ((GAIN * ls - GGAMMA * hy[c]) - GEPS * hz[c]);
            hy[c] = hy[c] + DT * hz[c];
            s[c] = ((hy[c] - 1.0f) - rf[c]) > 0.0f ? 1.0f : 0.0f;
            rf[c] = rf[c] * ref_decay + s[c];
            cnt[c] += s[c];
        }

        const unsigned long long ba = __ballot(s[0] > 0.0f);
        const unsigned long long bb = __ballot(s[1] > 0.0f);
        const unsigned long long bc = __ballot(s[2] > 0.0f);
        const unsigned long long bd = __ballot(s[3] > 0.0f);
        if (lane == 0)
            wcnt[wv] = (int)(__popcll(ba) + __popcll(bb) + __popcll(bc) + __popcll(bd));

        if (USE_XIN && ((t & 3) == 3)) {
            const int bufW = ((t >> 2) + 1) & 1;
            *reinterpret_cast<float4*>(&xstage[bufW][0][n0]) = P0;
            *reinterpret_cast<float4*>(&xstage[bufW][1][n0]) = P1;
            *reinterpret_cast<float4*>(&xstage[bufW][2][n0]) = P2;
            *reinterpret_cast<float4*>(&xstage[bufW][3][n0]) = P3;
            const int cNext = (t >> 2) + 2;
            if (cNext * 4 + 3 < T) {
                P0 = *reinterpret_cast<const float4*>(xrow + (size_t)(cNext * 4 + 0) * NH);
                P1 = *reinterpret_cast<const float4*>(xrow + (size_t)(cNext * 4 + 1) * NH);
                P2 = *reinterpret_cast<const float4*>(xrow + (size_t)(cNext * 4 + 2) * NH);
                P3 = *reinterpret_cast<const float4*>(xrow + (size_t)(cNext * 4 + 3) * NH);
            }
        }
        __syncthreads();

        const int4 c0 = *reinterpret_cast<const int4*>(&wcnt[0]);
        const int4 c1 = *reinterpret_cast<const int4*>(&wcnt[4]);
        int pre = 0;
        pre += (wv > 0) ? c0.x : 0;
        pre += (wv > 1) ? c0.y : 0;
        pre += (wv > 2) ? c0.z : 0;
        pre += (wv > 3) ? c0.w : 0;
        pre += (wv > 4) ? c1.x : 0;
        pre += (wv > 5) ? c1.y : 0;
        pre += (wv > 6) ? c1.z : 0;
        const int tot = ((c0.x + c0.y) + (c0.z + c0.w)) + ((c1.x + c1.y) + (c1.z + c1.w));

        const int gaLo = (int)__popcll(ba & lo32);
        const int gbLo = (int)__popcll(bb & lo32);
        const int gcLo = (int)__popcll(bc & lo32);
        const int gdLo = (int)__popcll(bd & lo32);
        const int g0 = gaLo + gcLo;
        const int g1 = gbLo + gdLo;
        const int g2 = (int)(__popcll(ba) + __popcll(bc)) - g0;
        const int base02 = (lane < 32) ? 0 : (g0 + g1);
        const int base13 = (lane < 32) ? g0 : ((g0 + g1) + g2);
        const int pa = (int)__popcll(ba & mb);
        const int pb = (int)__popcll(bb & mb);
        const int pc = (int)__popcll(bc & mb);
        const int pd = (int)__popcll(bd & mb);
        const int o02 = pre + base02 + pa + pc;
        const int o13 = pre + base13 + pb + pd;
        if (s[0] > 0.0f) list[o02] = n0;
        if (s[2] > 0.0f) list[o02 + (int)((ba >> lane) & 1ull)] = n0 + 2;
        if (s[1] > 0.0f) list[o13] = n0 + 1;
        if (s[3] > 0.0f) list[o13 + (int)((bb >> lane) & 1ull)] = n0 + 3;
        nact = tot;
        if (!USE_XIN) {
            if (t + 1 < T && tid < NI) xt[tid] = x[((size_t)b * T + (t + 1)) * NI + tid];
        }
        __syncthreads();
    }
#undef ISSUE1
#undef ACC1

    float4 o;
    o.x = cnt[0] / (float)T;
    o.y = cnt[1] / (float)T;
    o.z = cnt[2] / (float)T;
    o.w = cnt[3] / (float)T;
    *reinterpret_cast<float4*>(out + (size_t)b * NH + n0) = o;
}

extern "C" void kernel_launch(void* const* d_in, const int* in_sizes, int n_in,
                              void* d_out, int out_size, void* d_ws, size_t ws_size,
                              hipStream_t stream) {
    const float* x    = (const float*)d_in[0];   // [B,T,96]
    const float* x2h  = (const float*)d_in[1];   // [96,2048]
    const float* h2h  = (const float*)d_in[2];   // [2048,2048]
    const float* bias = (const float*)d_in[3];   // [2048]
    float* out = (float*)d_out;

    const int M = in_sizes[0] / NI;   // B*T
    const int T = 1024;
    const int B = M / T;

    const size_t xin_bytes = (size_t)M * NH * sizeof(float);
    if (ws_size >= xin_bytes) {
        float* xin = (float*)d_ws;
        dim3 grid(NH / 64, M / 64);
        xin_gemm<<<grid, 256, 0, stream>>>(x, x2h, xin);
        if ((B & 1) == 0 && B >= 2) {
            esn_dual<1><<<B / 2, 512, 0, stream>>>(xin, x, x2h, h2h, bias, out, T);
        } else {
            esn_seq1<1><<<B, 512, 0, stream>>>(xin, x, x2h, h2h, bias, out, T);
        }
    } else {
        if ((B & 1) == 0 && B >= 2) {
            esn_dual<0><<<B / 2, 512, 0, stream>>>(x /*unused*/, x, x2h, h2h, bias, out, T);
        } else {
            esn_seq1<0><<<B, 512, 0, stream>>>(x /*unused*/, x, x2h, h2h, bias, out, T);
        }
    }
}

// Round 9
// 1121.691 us; speedup vs baseline: 10.2539x; 1.6052x over previous
//
#include <hip/hip_runtime.h>
#include <cmath>

#define NH 2048
#define NI 96

// ---------------- GEMM: xin[b,t,:] = x[b,t,:] @ x2h  (no bias; bias added in seq kernel
// to match reference association order (xmul + smul) + bias) ----------------
__global__ __launch_bounds__(256) void xin_gemm(
    const float* __restrict__ A,
    const float* __restrict__ Bm,
    float* __restrict__ C)
{
    __shared__ float At[96][68];  // transposed A tile: At[k][r]
    __shared__ float Bt[96][68];  // Bt[k][c]
    const int tid = threadIdx.x;
    const int rowBase = blockIdx.y * 64;
    const int colBase = blockIdx.x * 64;

    {
        const int r = tid >> 2;
        const int sub = tid & 3;
        const float4* Arow = reinterpret_cast<const float4*>(A + (size_t)(rowBase + r) * NI);
        #pragma unroll
        for (int q = 0; q < 6; ++q) {
            const int k4 = sub + 4 * q;      // 0..23
            float4 v = Arow[k4];
            At[k4 * 4 + 0][r] = v.x;
            At[k4 * 4 + 1][r] = v.y;
            At[k4 * 4 + 2][r] = v.z;
            At[k4 * 4 + 3][r] = v.w;
        }
    }
    {
        const int c4 = tid & 15;
        const int k0 = tid >> 4;
        #pragma unroll
        for (int g = 0; g < 6; ++g) {
            const int kk = k0 + 16 * g;      // 0..95
            float4 v = *reinterpret_cast<const float4*>(Bm + (size_t)kk * NH + colBase + c4 * 4);
            *reinterpret_cast<float4*>(&Bt[kk][c4 * 4]) = v;
        }
    }
    __syncthreads();

    const int ty = tid >> 4, tx = tid & 15;
    float acc[4][4] = {};
    #pragma unroll 8
    for (int kk = 0; kk < 96; ++kk) {
        float4 a = *reinterpret_cast<const float4*>(&At[kk][ty * 4]);
        float4 b = *reinterpret_cast<const float4*>(&Bt[kk][tx * 4]);
        acc[0][0] += a.x * b.x; acc[0][1] += a.x * b.y; acc[0][2] += a.x * b.z; acc[0][3] += a.x * b.w;
        acc[1][0] += a.y * b.x; acc[1][1] += a.y * b.y; acc[1][2] += a.y * b.z; acc[1][3] += a.y * b.w;
        acc[2][0] += a.z * b.x; acc[2][1] += a.z * b.y; acc[2][2] += a.z * b.z; acc[2][3] += a.z * b.w;
        acc[3][0] += a.w * b.x; acc[3][1] += a.w * b.y; acc[3][2] += a.w * b.z; acc[3][3] += a.w * b.w;
    }
    #pragma unroll
    for (int i = 0; i < 4; ++i) {
        float4 o;
        o.x = acc[i][0]; o.y = acc[i][1]; o.z = acc[i][2]; o.w = acc[i][3];
        *reinterpret_cast<float4*>(C + (size_t)(rowBase + ty * 4 + i) * NH + colBase + tx * 4) = o;
    }
}

// ---------------- Sequential recurrence: one block per batch (R4 structure) ----------------
// PROVEN best configuration (R4: 960 us esn, 1122 us total). 512 threads;
// thread owns 4 neurons n0=4*tid..n0+3; 1 batch per block = 1 batch per CU.
// R8 measured why this is the roofline: per-CU load-return BW bound
// (~1600cy/step for nact*8KB of h2h rows at ~64B/cy) + ~650cy serial chain.
// Co-locating 2 batches/CU gave only 15% overlap (3840cy vs 2*2250) while
// halving active CUs -> regression. 1024-thread blocks are pinned to 64 VGPR
// by the backend (R5-R7, three attribute spellings ignored) -> spill.
// xin staged through LDS in 4-step chunks (double-buffered): per-step xin is
// an LDS read hidden under the gather; chunk loads issued 4 steps early.
// Gather row indices readfirstlane'd to SGPR base (saddr loads); 4-stage
// rotated load pipeline. Accumulation order: row at list position k -> a[k%4]
// for k<n4, tail rows fold into a0 in list order -> bit-exact (absmax 0.0).
template <int USE_XIN>
__global__ __launch_bounds__(512) void esn_seq(
    const float* __restrict__ xin,   // [B*T*NH] (xmul only) if USE_XIN
    const float* __restrict__ x,     // [B*T*NI] for fallback
    const float* __restrict__ x2h,   // [NI*NH]
    const float* __restrict__ h2h,   // [NH*NH]
    const float* __restrict__ bias,  // [NH]
    float* __restrict__ out,         // [B*NH]
    int T)
{
    const int b = blockIdx.x;
    const int tid = threadIdx.x;
    const int n0 = tid * 4;
    const int wv = tid >> 6;
    const int lane = tid & 63;

    __shared__ alignas(16) int list[NH];
    __shared__ alignas(16) int wcnt[8];
    __shared__ float xt[NI];
    __shared__ alignas(16) float xstage[2][4][NH];   // 64 KB: 2 bufs x 4 steps

    constexpr float DT = 0.075f;
    constexpr float TAU_M = 0.5f;
    constexpr float GGAMMA = 2.7f;
    constexpr float GEPS = 4.7f;
    constexpr float GAIN = 5.0f;
    const float ref_decay = expf(-0.075f / 0.25f);

    float lv[4] = {0.f, 0.f, 0.f, 0.f};
    float hy[4] = {0.f, 0.f, 0.f, 0.f};
    float hz[4] = {0.f, 0.f, 0.f, 0.f};
    float rf[4] = {0.f, 0.f, 0.f, 0.f};
    float cnt[4] = {0.f, 0.f, 0.f, 0.f};
    float bs[4];
    {
        const float4 b4 = *reinterpret_cast<const float4*>(&bias[n0]);
        bs[0] = b4.x; bs[1] = b4.y; bs[2] = b4.z; bs[3] = b4.w;
    }
    int nact = 0;

    const float* __restrict__ xrow = USE_XIN ? (xin + (size_t)b * T * NH + n0) : xin;

    // chunk-staging registers: hold the NEXT chunk (4 rows) of this thread's
    // 4 xin columns; written to LDS at the next boundary.
    float4 P0, P1, P2, P3;

    if (USE_XIN) {
        #pragma unroll
        for (int r = 0; r < 4; ++r) {
            float4 v = *reinterpret_cast<const float4*>(xrow + (size_t)r * NH);
            *reinterpret_cast<float4*>(&xstage[0][r][n0]) = v;
        }
        P0 = *reinterpret_cast<const float4*>(xrow + (size_t)4 * NH);
        P1 = *reinterpret_cast<const float4*>(xrow + (size_t)5 * NH);
        P2 = *reinterpret_cast<const float4*>(xrow + (size_t)6 * NH);
        P3 = *reinterpret_cast<const float4*>(xrow + (size_t)7 * NH);
    } else {
        if (tid < NI) xt[tid] = x[(size_t)b * T * NI + tid];
    }
    __syncthreads();

    const unsigned long long below = (1ull << lane) - 1ull;
    const unsigned long long lo32 = 0xFFFFFFFFull;
    const unsigned long long mb = (lane >= 32) ? (below & ~lo32) : below;

    const int4* __restrict__ L4 = reinterpret_cast<const int4*>(list);

// pipeline stage macros: ISSUE reads 1 int4 of indices (block-uniform ->
// readfirstlane to SGPR base) + 4 h2h rows (float4 each); ACC folds the stage
// into accumulators with the fixed pos%4 -> a{0..3} mapping.
#define ISSUE(St, grp) do {                                                              \
        I##St = L4[(grp)];                                                               \
        const float* pr0 = h2h + (size_t)__builtin_amdgcn_readfirstlane(I##St.x) * NH;   \
        const float* pr1 = h2h + (size_t)__builtin_amdgcn_readfirstlane(I##St.y) * NH;   \
        const float* pr2 = h2h + (size_t)__builtin_amdgcn_readfirstlane(I##St.z) * NH;   \
        const float* pr3 = h2h + (size_t)__builtin_amdgcn_readfirstlane(I##St.w) * NH;   \
        W##St##_0 = *reinterpret_cast<const float4*>(pr0 + n0);                          \
        W##St##_1 = *reinterpret_cast<const float4*>(pr1 + n0);                          \
        W##St##_2 = *reinterpret_cast<const float4*>(pr2 + n0);                          \
        W##St##_3 = *reinterpret_cast<const float4*>(pr3 + n0);                          \
    } while (0)
#define ACC(St) do {                                                                  \
        a0[0] += W##St##_0.x; a0[1] += W##St##_0.y; a0[2] += W##St##_0.z; a0[3] += W##St##_0.w; \
        a1[0] += W##St##_1.x; a1[1] += W##St##_1.y; a1[2] += W##St##_1.z; a1[3] += W##St##_1.w; \
        a2[0] += W##St##_2.x; a2[1] += W##St##_2.y; a2[2] += W##St##_2.z; a2[3] += W##St##_2.w; \
        a3[0] += W##St##_3.x; a3[1] += W##St##_3.y; a3[2] += W##St##_3.z; a3[3] += W##St##_3.w; \
    } while (0)

    for (int t = 0; t < T; ++t) {
        // ---- current step's xin row: LDS read, hidden under the gather.
        float4 xi;
        if (USE_XIN) xi = *reinterpret_cast<const float4*>(&xstage[(t >> 2) & 1][t & 3][n0]);

        // ---- phase 1: pipelined gather over active rows (prev step's s)
        float a0[4] = {0.f, 0.f, 0.f, 0.f};
        float a1[4] = {0.f, 0.f, 0.f, 0.f};
        float a2[4] = {0.f, 0.f, 0.f, 0.f};
        float a3[4] = {0.f, 0.f, 0.f, 0.f};

        const int n4 = nact & ~3;
        const int G = n4 >> 2;            // full groups of 4 rows
        const int tc = nact - n4;         // tail rows (0..3)

        int4 I0, I1, I2, I3;
        float4 W0_0, W0_1, W0_2, W0_3;
        float4 W1_0, W1_1, W1_2, W1_3;
        float4 W2_0, W2_1, W2_2, W2_3;
        float4 W3_0, W3_1, W3_2, W3_3;

        // prologue: fill up to 4 stages + tail rows (all issued before any wait)
        if (0 < G) ISSUE(0, 0);
        if (1 < G) ISSUE(1, 1);
        if (2 < G) ISSUE(2, 2);
        if (3 < G) ISSUE(3, 3);
        float4 tw0, tw1, tw2;
        if (tc > 0) {
            const float* p = h2h + (size_t)__builtin_amdgcn_readfirstlane(list[n4]) * NH;
            tw0 = *reinterpret_cast<const float4*>(p + n0);
        }
        if (tc > 1) {
            const float* p = h2h + (size_t)__builtin_amdgcn_readfirstlane(list[n4 + 1]) * NH;
            tw1 = *reinterpret_cast<const float4*>(p + n0);
        }
        if (tc > 2) {
            const float* p = h2h + (size_t)__builtin_amdgcn_readfirstlane(list[n4 + 2]) * NH;
            tw2 = *reinterpret_cast<const float4*>(p + n0);
        }

        // steady state: consume 4 stages, refill 4 stages (indices read first)
        int g = 0;
        for (; g + 4 <= G; g += 4) {
            const bool r0 = (g + 4 < G), r1 = (g + 5 < G), r2 = (g + 6 < G), r3 = (g + 7 < G);
            ACC(0); if (r0) ISSUE(0, g + 4);
            ACC(1); if (r1) ISSUE(1, g + 5);
            ACC(2); if (r2) ISSUE(2, g + 6);
            ACC(3); if (r3) ISSUE(3, g + 7);
        }
        // drain remaining issued stages (G - g in 0..3)
        if (g + 0 < G) ACC(0);
        if (g + 1 < G) ACC(1);
        if (g + 2 < G) ACC(2);
        // tail rows fold into a0, in list order (bit-exact vs old scalar tail)
        if (tc > 0) { a0[0] += tw0.x; a0[1] += tw0.y; a0[2] += tw0.z; a0[3] += tw0.w; }
        if (tc > 1) { a0[0] += tw1.x; a0[1] += tw1.y; a0[2] += tw1.z; a0[3] += tw1.w; }
        if (tc > 2) { a0[0] += tw2.x; a0[1] += tw2.y; a0[2] += tw2.z; a0[3] += tw2.w; }

        float ic[4];
        if (USE_XIN) {
            const float xiv[4] = {xi.x, xi.y, xi.z, xi.w};
            #pragma unroll
            for (int c = 0; c < 4; ++c) {
                const float rec = (a0[c] + a1[c]) + (a2[c] + a3[c]);
                ic[c] = (xiv[c] + rec) + bs[c];
            }
        } else {
            float m[4] = {0.f, 0.f, 0.f, 0.f};
            for (int i = 0; i < NI; ++i) {
                const float xv = xt[i];
                const float4 w = *reinterpret_cast<const float4*>(&x2h[(size_t)i * NH + n0]);
                m[0] += xv * w.x; m[1] += xv * w.y; m[2] += xv * w.z; m[3] += xv * w.w;
            }
            #pragma unroll
            for (int c = 0; c < 4; ++c) {
                const float rec = (a0[c] + a1[c]) + (a2[c] + a3[c]);
                ic[c] = (m[c] + rec) + bs[c];
            }
        }

        // ---- LIF + RF oscillator (same expressions/order as previous kernel)
        float s[4];
        #pragma unroll
        for (int c = 0; c < 4; ++c) {
            lv[c] = lv[c] + DT * (-lv[c] / TAU_M + ic[c]);
            const float ls = lv[c] > 1.0f ? 1.0f : 0.0f;
            lv[c] -= ls;
            hz[c] = hz[c] + DT * ((GAIN * ls - GGAMMA * hy[c]) - GEPS * hz[c]);
            hy[c] = hy[c] + DT * hz[c];
            s[c] = ((hy[c] - 1.0f) - rf[c]) > 0.0f ? 1.0f : 0.0f;
            rf[c] = rf[c] * ref_decay + s[c];
            cnt[c] += s[c];
        }

        // ---- compaction ballots (deterministic, order-preserving)
        const unsigned long long ba = __ballot(s[0] > 0.0f);
        const unsigned long long bb = __ballot(s[1] > 0.0f);
        const unsigned long long bc = __ballot(s[2] > 0.0f);
        const unsigned long long bd = __ballot(s[3] > 0.0f);
        if (lane == 0)
            wcnt[wv] = (int)(__popcll(ba) + __popcll(bb) + __popcll(bc) + __popcll(bd));

        // ---- chunk boundary: commit next chunk (P, loaded 4 steps ago -> no
        // stall) into the other buffer; issue loads for the chunk after that.
        if (USE_XIN && ((t & 3) == 3)) {
            const int bufW = ((t >> 2) + 1) & 1;
            *reinterpret_cast<float4*>(&xstage[bufW][0][n0]) = P0;
            *reinterpret_cast<float4*>(&xstage[bufW][1][n0]) = P1;
            *reinterpret_cast<float4*>(&xstage[bufW][2][n0]) = P2;
            *reinterpret_cast<float4*>(&xstage[bufW][3][n0]) = P3;
            const int cNext = (t >> 2) + 2;
            if (cNext * 4 + 3 < T) {
                P0 = *reinterpret_cast<const float4*>(xrow + (size_t)(cNext * 4 + 0) * NH);
                P1 = *reinterpret_cast<const float4*>(xrow + (size_t)(cNext * 4 + 1) * NH);
                P2 = *reinterpret_cast<const float4*>(xrow + (size_t)(cNext * 4 + 2) * NH);
                P3 = *reinterpret_cast<const float4*>(xrow + (size_t)(cNext * 4 + 3) * NH);
            }
        }
        __syncthreads();   // list reads done; wcnt + staged xin visible

        // ---- phase 2: cross-wave exclusive prefix (2 x int4 LDS reads)
        const int4 c0 = *reinterpret_cast<const int4*>(&wcnt[0]);
        const int4 c1 = *reinterpret_cast<const int4*>(&wcnt[4]);
        int pre = 0;
        pre += (wv > 0) ? c0.x : 0;
        pre += (wv > 1) ? c0.y : 0;
        pre += (wv > 2) ? c0.z : 0;
        pre += (wv > 3) ? c0.w : 0;
        pre += (wv > 4) ? c1.x : 0;
        pre += (wv > 5) ? c1.y : 0;
        pre += (wv > 6) ? c1.z : 0;
        const int tot = ((c0.x + c0.y) + (c0.z + c0.w)) + ((c1.x + c1.y) + (c1.z + c1.w));

        const int gaLo = (int)__popcll(ba & lo32);
        const int gbLo = (int)__popcll(bb & lo32);
        const int gcLo = (int)__popcll(bc & lo32);
        const int gdLo = (int)__popcll(bd & lo32);
        const int g0 = gaLo + gcLo;                                   // comps{0,2} lanes<32
        const int g1 = gbLo + gdLo;                                   // comps{1,3} lanes<32
        const int g2 = (int)(__popcll(ba) + __popcll(bc)) - g0;       // comps{0,2} lanes>=32
        const int base02 = (lane < 32) ? 0 : (g0 + g1);
        const int base13 = (lane < 32) ? g0 : ((g0 + g1) + g2);
        const int pa = (int)__popcll(ba & mb);
        const int pb = (int)__popcll(bb & mb);
        const int pc = (int)__popcll(bc & mb);
        const int pd = (int)__popcll(bd & mb);
        const int o02 = pre + base02 + pa + pc;
        const int o13 = pre + base13 + pb + pd;
        if (s[0] > 0.0f) list[o02] = n0;
        if (s[2] > 0.0f) list[o02 + (int)((ba >> lane) & 1ull)] = n0 + 2;
        if (s[1] > 0.0f) list[o13] = n0 + 1;
        if (s[3] > 0.0f) list[o13 + (int)((bb >> lane) & 1ull)] = n0 + 3;
        nact = tot;
        if (!USE_XIN) {
            if (t + 1 < T && tid < NI) xt[tid] = x[((size_t)b * T + (t + 1)) * NI + tid];
        }
        __syncthreads();   // list visible for next step
    }
#undef ISSUE
#undef ACC

    float4 o;
    o.x = cnt[0] / (float)T;
    o.y = cnt[1] / (float)T;
    o.z = cnt[2] / (float)T;
    o.w = cnt[3] / (float)T;
    *reinterpret_cast<float4*>(out + (size_t)b * NH + n0) = o;
}

extern "C" void kernel_launch(void* const* d_in, const int* in_sizes, int n_in,
                              void* d_out, int out_size, void* d_ws, size_t ws_size,
                              hipStream_t stream) {
    const float* x    = (const float*)d_in[0];   // [B,T,96]
    const float* x2h  = (const float*)d_in[1];   // [96,2048]
    const float* h2h  = (const float*)d_in[2];   // [2048,2048]
    const float* bias = (const float*)d_in[3];   // [2048]
    float* out = (float*)d_out;

    const int M = in_sizes[0] / NI;   // B*T
    const int T = 1024;
    const int B = M / T;

    const size_t xin_bytes = (size_t)M * NH * sizeof(float);
    if (ws_size >= xin_bytes) {
        float* xin = (float*)d_ws;
        dim3 grid(NH / 64, M / 64);
        xin_gemm<<<grid, 256, 0, stream>>>(x, x2h, xin);
        esn_seq<1><<<B, 512, 0, stream>>>(xin, x, x2h, h2h, bias, out, T);
    } else {
        esn_seq<0><<<B, 512, 0, stream>>>(x /*unused as xin*/, x, x2h, h2h, bias, out, T);
    }
}